// Round 1
// baseline (3849.678 us; speedup 1.0000x reference)
//
#include <hip/hip_runtime.h>
#include <cstdint>
#include <cstddef>

#define NB 4
#define NN 4096
#define KK 16
#define DP 64
#define DM 128
#define EPS 1e-5f

__device__ __forceinline__ float lrelu(float x){ return x >= 0.f ? x : 0.2f*x; }

__device__ __forceinline__ unsigned short f2bf(float x){
  union { float f; uint32_t u; } a; a.f = x;
  return (unsigned short)((a.u + 0x7fffu + ((a.u >> 16) & 1u)) >> 16);
}
__device__ __forceinline__ float bfl(uint32_t w){ return __uint_as_float(w << 16); }
__device__ __forceinline__ float bfh(uint32_t w){ return __uint_as_float(w & 0xffff0000u); }

// ---------------------------------------------------------------- sq norms
__global__ __launch_bounds__(256) void k_sqnorm(const float* __restrict__ feats,
                                                float* __restrict__ sqn){
  const int i = blockIdx.x*256 + threadIdx.x;
  const int b = i >> 12, n = i & (NN-1);
  const float* f = feats + (size_t)b*DP*NN + n;
  float s = 0.f;
  #pragma unroll
  for (int c=0;c<DP;c++){ const float v = f[(size_t)c*NN]; s += v*v; }
  sqn[i] = s;
}

// ---------------------------------------------------------------- x = lrelu(bn1(W1@feats)), point-major out
__global__ __launch_bounds__(256) void k_x(const float* __restrict__ feats,
                                           const float* __restrict__ W1,
                                           const float* __restrict__ bn1,
                                           float* __restrict__ x_ws){
  __shared__ float W1s[DM][DP+1];
  __shared__ float ft[DP][64];
  __shared__ float bS[DM], bT[DM];
  const int t = threadIdx.x;
  const int b = blockIdx.x >> 6;
  const int n0 = (blockIdx.x & 63) * 64;
  for (int i=t; i<DM*DP; i+=256){ W1s[i>>6][i&63] = W1[i]; }
  if (t < DM){
    float g = bn1[t], be = bn1[DM+t], mn = bn1[2*DM+t], vr = bn1[3*DM+t];
    float s = g*rsqrtf(vr+EPS); bS[t]=s; bT[t]=be-mn*s;
  }
  for (int i=t; i<DP*64; i+=256){
    const int c = i>>6, j = i&63;
    ft[c][j] = feats[(size_t)b*DP*NN + (size_t)c*NN + n0 + j];
  }
  __syncthreads();
  const int j = t >> 2, cq = t & 3;
  float acc[32];
  #pragma unroll
  for (int i=0;i<32;i++) acc[i]=0.f;
  for (int c=0;c<DP;c++){
    const float fv = ft[c][j];
    #pragma unroll
    for (int i=0;i<32;i++) acc[i] += W1s[cq+4*i][c]*fv;
  }
  float* xo = x_ws + ((size_t)(b*NN) + n0 + j)*DM;
  #pragma unroll
  for (int i=0;i<32;i++){
    const int ch = cq + 4*i;
    xo[ch] = lrelu(acc[i]*bS[ch] + bT[ch]);
  }
}

// ---------------------------------------------------------------- q/k/v = W{q,k,v} @ x, point-major out
__global__ __launch_bounds__(256) void k_qkv(const float* __restrict__ x_ws,
                                             const float* __restrict__ Wq,
                                             const float* __restrict__ Wk,
                                             const float* __restrict__ Wv,
                                             float* __restrict__ q_ws,
                                             float* __restrict__ k_ws,
                                             float* __restrict__ v_ws){
  __shared__ float Ws[DM][DM+4];   // stride 132 (16B-aligned rows, bank-spread)
  __shared__ float xt[64][DM+4];
  const int t = threadIdx.x;
  const int b = blockIdx.x >> 6;
  const int n0 = (blockIdx.x & 63) * 64;
  for (int i=t; i<64*DM; i+=256){
    const int j = i>>7, c = i&127;
    xt[j][c] = x_ws[((size_t)(b*NN) + n0 + j)*DM + c];
  }
  const float* Wp[3] = {Wq, Wk, Wv};
  float* Op[3] = {q_ws, k_ws, v_ws};
  for (int wi=0; wi<3; wi++){
    __syncthreads();
    for (int i=t; i<DM*DM; i+=256){ Ws[i>>7][i&127] = Wp[wi][i]; }
    __syncthreads();
    const int j = t>>2, cq = t&3;
    float acc[32];
    #pragma unroll
    for (int i=0;i<32;i++) acc[i]=0.f;
    for (int c=0;c<DM;c+=4){
      const float4 xv = *reinterpret_cast<const float4*>(&xt[j][c]);
      #pragma unroll
      for (int i=0;i<32;i++){
        const float4 wv = *reinterpret_cast<const float4*>(&Ws[cq+4*i][c]);
        acc[i] += wv.x*xv.x + wv.y*xv.y + wv.z*xv.z + wv.w*xv.w;
      }
    }
    float* op = Op[wi] + ((size_t)(b*NN) + n0 + j)*DM;
    #pragma unroll
    for (int i=0;i<32;i++) op[cq+4*i] = acc[i];
  }
}

// ---------------------------------------------------------------- kNN (top-16 smallest sq-dist, self included)
__global__ __launch_bounds__(256) void k_knn(const float* __restrict__ feats,
                                             const float* __restrict__ sqn,
                                             int* __restrict__ idx_ws){
  __shared__ float fc[DP][256];     // 64 KiB; reused as merge buffer afterwards
  __shared__ float sc[256];
  const int t = threadIdx.x;
  const int b = blockIdx.x >> 7;
  const int q0 = (blockIdx.x & 127) * 32;
  const int ql = t & 31, part = t >> 5;          // 8 candidate-parts per query
  const int q = q0 + ql;
  const float* fb = feats + (size_t)b*DP*NN;
  float qf[DP];
  #pragma unroll
  for (int c=0;c<DP;c++) qf[c] = fb[(size_t)c*NN + q];
  const float sqq = sqn[b*NN + q];
  float dd[16]; int ii[16];
  #pragma unroll
  for (int s=0;s<16;s++){ dd[s]=3.4e38f; ii[s]=0; }
  float dmax = 3.4e38f;

  for (int m0t=0; m0t<NN; m0t+=256){
    __syncthreads();
    for (int i=t; i<DP*256; i+=256){
      const int c = i >> 8, j = i & 255;
      fc[c][j] = fb[(size_t)c*NN + m0t + j];
    }
    sc[t] = sqn[b*NN + m0t + t];
    __syncthreads();
    const int j0 = part*32;
    for (int j=j0; j<j0+32; j+=4){
      float a0=0.f,a1=0.f,a2=0.f,a3=0.f;
      #pragma unroll
      for (int c=0;c<DP;c++){
        const float4 fv = *reinterpret_cast<const float4*>(&fc[c][j]);
        const float qc = qf[c];
        a0 += qc*fv.x; a1 += qc*fv.y; a2 += qc*fv.z; a3 += qc*fv.w;
      }
      float d[4];
      d[0] = sqq + sc[j]   - 2.f*a0;
      d[1] = sqq + sc[j+1] - 2.f*a1;
      d[2] = sqq + sc[j+2] - 2.f*a2;
      d[3] = sqq + sc[j+3] - 2.f*a3;
      #pragma unroll
      for (int u=0;u<4;u++){
        if (d[u] < dmax){
          bool done=false;
          #pragma unroll
          for (int s=0;s<16;s++){
            if (!done && dd[s]==dmax){ dd[s]=d[u]; ii[s]=m0t+j+u; done=true; }
          }
          dmax = dd[0];
          #pragma unroll
          for (int s=1;s<16;s++) dmax = fmaxf(dmax, dd[s]);
        }
      }
    }
  }
  __syncthreads();
  // merge 8 partial lists per query: rows padded to 129 (bank-conflict-free scans)
  float* mD = &fc[0][0];
  int*   mI = reinterpret_cast<int*>(&fc[32][0]);
  #pragma unroll
  for (int s=0;s<16;s++){
    mD[ql*129 + part*16 + s] = dd[s];
    mI[ql*129 + part*16 + s] = ii[s];
  }
  __syncthreads();
  if (t < 32){
    int* op = idx_ws + ((size_t)(b*NN) + q0 + t)*KK;
    float* rowD = mD + t*129;
    int*   rowI = mI + t*129;
    for (int s=0;s<KK;s++){
      float best = rowD[0]; int bi = 0;
      for (int e=1;e<128;e++){
        const float dv = rowD[e];
        if (dv < best){ best=dv; bi=e; }
      }
      op[s] = rowI[bi];
      rowD[bi] = 3.4e38f;
    }
  }
}

// ---------------------------------------------------------------- fused pe/attn/softmax/reduce
// bf16 weights in LDS, XOR-swizzled 8-element granules: row c, logical granule g stored at g^(c&15)
__device__ __forceinline__ void mv128(const unsigned short* __restrict__ Wlds,
                                      const float* __restrict__ hv, int l,
                                      float& o0, float& o1){
  float a0=0.f, a1=0.f;
  const int sw = l & 15;
  #pragma unroll
  for (int g=0; g<16; ++g){
    const int p = g ^ sw;
    const uint4 w0 = *reinterpret_cast<const uint4*>(&Wlds[l*DM + p*8]);
    const uint4 w1 = *reinterpret_cast<const uint4*>(&Wlds[(l+64)*DM + p*8]);
    const float4 ha = *reinterpret_cast<const float4*>(&hv[g*8]);
    const float4 hb = *reinterpret_cast<const float4*>(&hv[g*8+4]);
    a0 += bfl(w0.x)*ha.x + bfh(w0.x)*ha.y + bfl(w0.y)*ha.z + bfh(w0.y)*ha.w;
    a0 += bfl(w0.z)*hb.x + bfh(w0.z)*hb.y + bfl(w0.w)*hb.z + bfh(w0.w)*hb.w;
    a1 += bfl(w1.x)*ha.x + bfh(w1.x)*ha.y + bfl(w1.y)*ha.z + bfh(w1.y)*ha.w;
    a1 += bfl(w1.z)*hb.x + bfh(w1.z)*hb.y + bfl(w1.w)*hb.z + bfh(w1.w)*hb.w;
  }
  o0 = a0; o1 = a1;
}

__global__ __launch_bounds__(512) void k_attn(
    const float* __restrict__ pos, const float* __restrict__ q_ws,
    const float* __restrict__ k_ws, const float* __restrict__ v_ws,
    const int* __restrict__ idx_ws,
    const float* __restrict__ Wd1, const float* __restrict__ bnd1,
    const float* __restrict__ Wd2, const float* __restrict__ bnd2,
    const float* __restrict__ Wg1, const float* __restrict__ bng1,
    const float* __restrict__ Wg2, const float* __restrict__ bng2,
    float* __restrict__ res_ws){
  __shared__ unsigned short Wd2s[DM*DM];
  __shared__ unsigned short Wg1s[DM*DM];
  __shared__ unsigned short Wg2s[DM*DM];
  __shared__ float Wd1s[DM*4];
  __shared__ float bnS[4][DM], bnT[4][DM];
  __shared__ float hA[8][DM], hB[8][DM], hC[8][DM];

  const int t = threadIdx.x, w = t >> 6, l = t & 63;

  if (t < DM){
    const float* bp[4] = {bnd1, bnd2, bng1, bng2};
    #pragma unroll
    for (int s=0;s<4;s++){
      float g = bp[s][t], be = bp[s][DM+t], mn = bp[s][2*DM+t], vr = bp[s][3*DM+t];
      float sc = g * rsqrtf(vr + EPS);
      bnS[s][t] = sc; bnT[s][t] = be - mn*sc;
    }
    Wd1s[t*4+0] = Wd1[t*3+0];
    Wd1s[t*4+1] = Wd1[t*3+1];
    Wd1s[t*4+2] = Wd1[t*3+2];
    Wd1s[t*4+3] = 0.f;
  }
  {
    const float* wsrc[3] = {Wd2, Wg1, Wg2};
    unsigned short* wdst[3] = {Wd2s, Wg1s, Wg2s};
    #pragma unroll
    for (int wi=0; wi<3; wi++){
      const float* src = wsrc[wi];
      unsigned short* dst = wdst[wi];
      for (int i=t; i<(DM*DM)/8; i+=512){
        const int ch = i >> 4, g = i & 15;
        const float* sp = src + ch*DM + g*8;
        const uint32_t d0 = (uint32_t)f2bf(sp[0]) | ((uint32_t)f2bf(sp[1])<<16);
        const uint32_t d1 = (uint32_t)f2bf(sp[2]) | ((uint32_t)f2bf(sp[3])<<16);
        const uint32_t d2 = (uint32_t)f2bf(sp[4]) | ((uint32_t)f2bf(sp[5])<<16);
        const uint32_t d3 = (uint32_t)f2bf(sp[6]) | ((uint32_t)f2bf(sp[7])<<16);
        const int p = g ^ (ch & 15);
        *reinterpret_cast<uint4*>(&dst[ch*DM + p*8]) = make_uint4(d0,d1,d2,d3);
      }
    }
  }
  __syncthreads();

  const int c0 = l, c1 = l + 64;
  const int pbase = blockIdx.x * 64 + w * 8;
  for (int pp=0; pp<8; ++pp){
    const int gp = pbase + pp;
    const int b = gp >> 12, n = gp & (NN-1);
    const float* posb = pos + (size_t)b*3*NN;
    const float px = posb[n], py = posb[NN+n], pz = posb[2*NN+n];
    const float qv0 = q_ws[(size_t)gp*DM + c0];
    const float qv1 = q_ws[(size_t)gp*DM + c1];
    const int* ip = idx_ws + (size_t)gp*KK;
    float m0=-3.4e38f, m1=-3.4e38f, s0=0.f, s1=0.f, r0=0.f, r1=0.f;
    for (int k=0;k<KK;k++){
      const int mi = ip[k];
      const float rx = px - posb[mi];
      const float ry = py - posb[NN+mi];
      const float rz = pz - posb[2*NN+mi];
      // layer d1 (3 -> 128) + bn + lrelu
      float h0 = Wd1s[c0*4]*rx + Wd1s[c0*4+1]*ry + Wd1s[c0*4+2]*rz;
      float h1 = Wd1s[c1*4]*rx + Wd1s[c1*4+1]*ry + Wd1s[c1*4+2]*rz;
      h0 = lrelu(h0*bnS[0][c0] + bnT[0][c0]);
      h1 = lrelu(h1*bnS[0][c1] + bnT[0][c1]);
      hA[w][c0]=h0; hA[w][c1]=h1;
      float pe0, pe1; mv128(Wd2s, hA[w], l, pe0, pe1);
      pe0 = lrelu(pe0*bnS[1][c0] + bnT[1][c0]);
      pe1 = lrelu(pe1*bnS[1][c1] + bnT[1][c1]);
      // a0 = q - kf + pe
      const float* kp = k_ws + ((size_t)(b*NN) + mi)*DM;
      hB[w][c0] = qv0 - kp[c0] + pe0;
      hB[w][c1] = qv1 - kp[c1] + pe1;
      float g0, g1v; mv128(Wg1s, hB[w], l, g0, g1v);
      g0  = lrelu(g0 *bnS[2][c0] + bnT[2][c0]);
      g1v = lrelu(g1v*bnS[2][c1] + bnT[2][c1]);
      hC[w][c0]=g0; hC[w][c1]=g1v;
      float av0, av1; mv128(Wg2s, hC[w], l, av0, av1);
      av0 = lrelu(av0*bnS[3][c0] + bnT[3][c0]);
      av1 = lrelu(av1*bnS[3][c1] + bnT[3][c1]);
      // online softmax over K (temperature sqrt(N)=64), per channel
      const float L0 = av0 * (1.f/64.f), L1 = av1 * (1.f/64.f);
      const float* vp = v_ws + ((size_t)(b*NN) + mi)*DM;
      const float val0 = vp[c0] + pe0, val1 = vp[c1] + pe1;
      float nm = fmaxf(m0, L0);
      float e  = __expf(L0-nm), scl = __expf(m0-nm);
      s0 = s0*scl + e; r0 = r0*scl + e*val0; m0 = nm;
      nm = fmaxf(m1, L1);
      e  = __expf(L1-nm); scl = __expf(m1-nm);
      s1 = s1*scl + e; r1 = r1*scl + e*val1; m1 = nm;
    }
    res_ws[(size_t)gp*DM + c0] = r0/s0;
    res_ws[(size_t)gp*DM + c1] = r1/s1;
  }
}

// ---------------------------------------------------------------- out = lrelu(bn2(W2@res)) + feats
__global__ __launch_bounds__(256) void k_out(const float* __restrict__ res_ws,
                                             const float* __restrict__ W2,
                                             const float* __restrict__ bn2,
                                             const float* __restrict__ feats,
                                             float* __restrict__ out){
  __shared__ float W2s[DP][DM+4];
  __shared__ float rt[128][DM+4];
  __shared__ float ob[DP][132];
  __shared__ float bS[DP], bT[DP];
  const int t = threadIdx.x;
  const int b = blockIdx.x >> 5;
  const int n0 = (blockIdx.x & 31) * 128;
  for (int i=t; i<DP*DM; i+=256){ W2s[i>>7][i&127] = W2[i]; }
  if (t < DP){
    float g=bn2[t], be=bn2[DP+t], mn=bn2[2*DP+t], vr=bn2[3*DP+t];
    float s = g*rsqrtf(vr+EPS); bS[t]=s; bT[t]=be-mn*s;
  }
  for (int i=t; i<128*DM; i+=256){
    const int j=i>>7, c=i&127;
    rt[j][c] = res_ws[((size_t)(b*NN)+n0+j)*DM + c];
  }
  __syncthreads();
  const int j = t>>1, cq = t&1;
  float acc[32];
  #pragma unroll
  for (int i=0;i<32;i++) acc[i]=0.f;
  for (int c=0;c<DM;c+=4){
    const float4 rv = *reinterpret_cast<const float4*>(&rt[j][c]);
    #pragma unroll
    for (int i=0;i<32;i++){
      const float4 wv = *reinterpret_cast<const float4*>(&W2s[cq+2*i][c]);
      acc[i] += wv.x*rv.x + wv.y*rv.y + wv.z*rv.z + wv.w*rv.w;
    }
  }
  #pragma unroll
  for (int i=0;i<32;i++) ob[cq+2*i][j] = acc[i];
  __syncthreads();
  for (int i=t; i<DP*128; i+=256){
    const int ch=i>>7, jj=i&127;
    const size_t o = (size_t)b*DP*NN + (size_t)ch*NN + n0 + jj;
    out[o] = lrelu(ob[ch][jj]*bS[ch] + bT[ch]) + feats[o];
  }
}

// ----------------------------------------------------------------
extern "C" void kernel_launch(void* const* d_in, const int* in_sizes, int n_in,
                              void* d_out, int out_size, void* d_ws, size_t ws_size,
                              hipStream_t stream) {
  const float* feats = (const float*)d_in[0];
  const float* pos   = (const float*)d_in[1];
  const float* W1    = (const float*)d_in[2];
  const float* bn1   = (const float*)d_in[3];
  const float* W2    = (const float*)d_in[4];
  const float* bn2   = (const float*)d_in[5];
  const float* Wq    = (const float*)d_in[6];
  const float* Wk    = (const float*)d_in[7];
  const float* Wv    = (const float*)d_in[8];
  const float* Wd1   = (const float*)d_in[9];
  const float* bnd1  = (const float*)d_in[10];
  const float* Wd2   = (const float*)d_in[11];
  const float* bnd2  = (const float*)d_in[12];
  const float* Wg1   = (const float*)d_in[13];
  const float* bng1  = (const float*)d_in[14];
  const float* Wg2   = (const float*)d_in[15];
  const float* bng2  = (const float*)d_in[16];
  float* out = (float*)d_out;

  float* ws   = (float*)d_ws;
  float* q_ws = ws;                           // B*N*DM
  float* k_ws = q_ws + (size_t)NB*NN*DM;
  float* v_ws = k_ws + (size_t)NB*NN*DM;
  float* x_ws = v_ws + (size_t)NB*NN*DM;      // reused as res_ws after k_qkv
  float* sqn  = x_ws + (size_t)NB*NN*DM;
  int*   idx  = (int*)(sqn + (size_t)NB*NN);

  k_sqnorm<<<(NB*NN)/256, 256, 0, stream>>>(feats, sqn);
  k_x     <<<NB*(NN/64), 256, 0, stream>>>(feats, W1, bn1, x_ws);
  k_qkv   <<<NB*(NN/64), 256, 0, stream>>>(x_ws, Wq, Wk, Wv, q_ws, k_ws, v_ws);
  k_knn   <<<NB*(NN/32), 256, 0, stream>>>(feats, sqn, idx);
  k_attn  <<<(NB*NN)/64, 512, 0, stream>>>(pos, q_ws, k_ws, v_ws, idx,
                                           Wd1, bnd1, Wd2, bnd2,
                                           Wg1, bng1, Wg2, bng2,
                                           x_ws /* res, overwrites x */);
  k_out   <<<NB*(NN/128), 256, 0, stream>>>(x_ws, W2, bn2, feats, out);
}

// Round 2
// 1766.236 us; speedup vs baseline: 2.1796x; 2.1796x over previous
//
#include <hip/hip_runtime.h>
#include <cstdint>
#include <cstddef>

#define NB 4
#define NN 4096
#define KK 16
#define DP 64
#define DM 128
#define EPS 1e-5f

typedef __attribute__((ext_vector_type(8))) short bf16x8;
typedef __attribute__((ext_vector_type(4))) float f32x4;

__device__ __forceinline__ float lrelu(float x){ return x >= 0.f ? x : 0.2f*x; }

__device__ __forceinline__ unsigned short f2bf(float x){
  union { float f; uint32_t u; } a; a.f = x;
  return (unsigned short)((a.u + 0x7fffu + ((a.u >> 16) & 1u)) >> 16);
}
__device__ __forceinline__ uint32_t pk2(float a, float b){
  return (uint32_t)f2bf(a) | ((uint32_t)f2bf(b) << 16);
}
__device__ __forceinline__ float bfl(uint32_t w){ return __uint_as_float(w << 16); }
__device__ __forceinline__ float bfh(uint32_t w){ return __uint_as_float(w & 0xffff0000u); }

__device__ __forceinline__ f32x4 mfma16(bf16x8 a, bf16x8 b, f32x4 c){
  return __builtin_amdgcn_mfma_f32_16x16x32_bf16(a, b, c, 0, 0, 0);
}
__device__ __forceinline__ float sx16(float v, int m){ return __shfl_xor(v, m, 16); }

// ---------------------------------------------------------------- sq norms
__global__ __launch_bounds__(256) void k_sqnorm(const float* __restrict__ feats,
                                                float* __restrict__ sqn){
  const int i = blockIdx.x*256 + threadIdx.x;
  const int b = i >> 12, n = i & (NN-1);
  const float* f = feats + (size_t)b*DP*NN + n;
  float s = 0.f;
  #pragma unroll
  for (int c=0;c<DP;c++){ const float v = f[(size_t)c*NN]; s += v*v; }
  sqn[i] = s;
}

// ---------------------------------------------------------------- x = lrelu(bn1(W1@feats)), point-major out
__global__ __launch_bounds__(256) void k_x(const float* __restrict__ feats,
                                           const float* __restrict__ W1,
                                           const float* __restrict__ bn1,
                                           float* __restrict__ x_ws){
  __shared__ float W1s[DM][DP+1];
  __shared__ float ft[DP][64];
  __shared__ float bS[DM], bT[DM];
  const int t = threadIdx.x;
  const int b = blockIdx.x >> 6;
  const int n0 = (blockIdx.x & 63) * 64;
  for (int i=t; i<DM*DP; i+=256){ W1s[i>>6][i&63] = W1[i]; }
  if (t < DM){
    float g = bn1[t], be = bn1[DM+t], mn = bn1[2*DM+t], vr = bn1[3*DM+t];
    float s = g*rsqrtf(vr+EPS); bS[t]=s; bT[t]=be-mn*s;
  }
  for (int i=t; i<DP*64; i+=256){
    const int c = i>>6, j = i&63;
    ft[c][j] = feats[(size_t)b*DP*NN + (size_t)c*NN + n0 + j];
  }
  __syncthreads();
  const int j = t >> 2, cq = t & 3;
  float acc[32];
  #pragma unroll
  for (int i=0;i<32;i++) acc[i]=0.f;
  for (int c=0;c<DP;c++){
    const float fv = ft[c][j];
    #pragma unroll
    for (int i=0;i<32;i++) acc[i] += W1s[cq+4*i][c]*fv;
  }
  float* xo = x_ws + ((size_t)(b*NN) + n0 + j)*DM;
  #pragma unroll
  for (int i=0;i<32;i++){
    const int ch = cq + 4*i;
    xo[ch] = lrelu(acc[i]*bS[ch] + bT[ch]);
  }
}

// ---------------------------------------------------------------- q/k/v = W{q,k,v} @ x, point-major out
__global__ __launch_bounds__(256) void k_qkv(const float* __restrict__ x_ws,
                                             const float* __restrict__ Wq,
                                             const float* __restrict__ Wk,
                                             const float* __restrict__ Wv,
                                             float* __restrict__ q_ws,
                                             float* __restrict__ k_ws,
                                             float* __restrict__ v_ws){
  __shared__ float Ws[DM][DM+4];
  __shared__ float xt[64][DM+4];
  const int t = threadIdx.x;
  const int b = blockIdx.x >> 6;
  const int n0 = (blockIdx.x & 63) * 64;
  for (int i=t; i<64*DM; i+=256){
    const int j = i>>7, c = i&127;
    xt[j][c] = x_ws[((size_t)(b*NN) + n0 + j)*DM + c];
  }
  const float* Wp[3] = {Wq, Wk, Wv};
  float* Op[3] = {q_ws, k_ws, v_ws};
  for (int wi=0; wi<3; wi++){
    __syncthreads();
    for (int i=t; i<DM*DM; i+=256){ Ws[i>>7][i&127] = Wp[wi][i]; }
    __syncthreads();
    const int j = t>>2, cq = t&3;
    float acc[32];
    #pragma unroll
    for (int i=0;i<32;i++) acc[i]=0.f;
    for (int c=0;c<DM;c+=4){
      const float4 xv = *reinterpret_cast<const float4*>(&xt[j][c]);
      #pragma unroll
      for (int i=0;i<32;i++){
        const float4 wv = *reinterpret_cast<const float4*>(&Ws[cq+4*i][c]);
        acc[i] += wv.x*xv.x + wv.y*xv.y + wv.z*xv.z + wv.w*xv.w;
      }
    }
    float* op = Op[wi] + ((size_t)(b*NN) + n0 + j)*DM;
    #pragma unroll
    for (int i=0;i<32;i++) op[cq+4*i] = acc[i];
  }
}

// ---------------------------------------------------------------- kNN (top-16 smallest sq-dist)
__global__ __launch_bounds__(256) void k_knn(const float* __restrict__ feats,
                                             const float* __restrict__ sqn,
                                             int* __restrict__ idx_ws){
  __shared__ float fc[DP][256];
  __shared__ float sc[256];
  const int t = threadIdx.x;
  const int b = blockIdx.x >> 7;
  const int q0 = (blockIdx.x & 127) * 32;
  const int ql = t & 31, part = t >> 5;
  const int q = q0 + ql;
  const float* fb = feats + (size_t)b*DP*NN;
  float qf[DP];
  #pragma unroll
  for (int c=0;c<DP;c++) qf[c] = fb[(size_t)c*NN + q];
  const float sqq = sqn[b*NN + q];
  float dd[16]; int ii[16];
  #pragma unroll
  for (int s=0;s<16;s++){ dd[s]=3.4e38f; ii[s]=0; }
  float dmax = 3.4e38f;

  for (int m0t=0; m0t<NN; m0t+=256){
    __syncthreads();
    for (int i=t; i<DP*256; i+=256){
      const int c = i >> 8, j = i & 255;
      fc[c][j] = fb[(size_t)c*NN + m0t + j];
    }
    sc[t] = sqn[b*NN + m0t + t];
    __syncthreads();
    const int j0 = part*32;
    for (int j=j0; j<j0+32; j+=4){
      float a0=0.f,a1=0.f,a2=0.f,a3=0.f;
      #pragma unroll
      for (int c=0;c<DP;c++){
        const float4 fv = *reinterpret_cast<const float4*>(&fc[c][j]);
        const float qc = qf[c];
        a0 += qc*fv.x; a1 += qc*fv.y; a2 += qc*fv.z; a3 += qc*fv.w;
      }
      float d[4];
      d[0] = sqq + sc[j]   - 2.f*a0;
      d[1] = sqq + sc[j+1] - 2.f*a1;
      d[2] = sqq + sc[j+2] - 2.f*a2;
      d[3] = sqq + sc[j+3] - 2.f*a3;
      #pragma unroll
      for (int u=0;u<4;u++){
        if (d[u] < dmax){
          bool done=false;
          #pragma unroll
          for (int s=0;s<16;s++){
            if (!done && dd[s]==dmax){ dd[s]=d[u]; ii[s]=m0t+j+u; done=true; }
          }
          dmax = dd[0];
          #pragma unroll
          for (int s=1;s<16;s++) dmax = fmaxf(dmax, dd[s]);
        }
      }
    }
  }
  __syncthreads();
  float* mD = &fc[0][0];
  int*   mI = reinterpret_cast<int*>(&fc[32][0]);
  #pragma unroll
  for (int s=0;s<16;s++){
    mD[ql*129 + part*16 + s] = dd[s];
    mI[ql*129 + part*16 + s] = ii[s];
  }
  __syncthreads();
  if (t < 32){
    int* op = idx_ws + ((size_t)(b*NN) + q0 + t)*KK;
    float* rowD = mD + t*129;
    int*   rowI = mI + t*129;
    for (int s=0;s<KK;s++){
      float best = rowD[0]; int bi = 0;
      for (int e=1;e<128;e++){
        const float dv = rowD[e];
        if (dv < best){ best=dv; bi=e; }
      }
      op[s] = rowI[bi];
      rowD[bi] = 3.4e38f;
    }
  }
}

// ---------------------------------------------------------------- weight prep: bf16 MFMA fragments, bn-scale folded
// frag f: 0..95 -> mat(0=Wd2,1=Wg1,2=Wg2)*32 + chtile*4 + kslice; 96..103 -> Wd1' chtile
// layout: wfrag[(f*64 + lane)*8 + j] = bf16( s_row * W[row][k] ),
//   row = chtile*16 + (lane&15), k = kslice*32 + (lane>>4)*8 + j
__global__ __launch_bounds__(256) void k_wprep(
    const float* __restrict__ Wd1, const float* __restrict__ bnd1,
    const float* __restrict__ Wd2, const float* __restrict__ bnd2,
    const float* __restrict__ Wg1, const float* __restrict__ bng1,
    const float* __restrict__ Wg2, const float* __restrict__ bng2,
    unsigned short* __restrict__ wfrag){
  const int i = blockIdx.x*256 + threadIdx.x;
  if (i >= 104*64) return;
  const int f = i >> 6, l = i & 63;
  const int r16 = l & 15, kg = (l >> 4) * 8;
  unsigned short o8[8];
  if (f < 96){
    const int mat = f >> 5, tt = (f >> 2) & 7, ks = f & 3;
    const float* W; const float* bn;
    if (mat == 0){ W = Wd2; bn = bnd2; }
    else if (mat == 1){ W = Wg1; bn = bng1; }
    else { W = Wg2; bn = bng2; }
    const int row = tt*16 + r16;
    const float s = bn[row] * rsqrtf(bn[3*DM+row] + EPS);
    const float* src = W + (size_t)row*DM + ks*32 + kg;
    #pragma unroll
    for (int j=0;j<8;j++) o8[j] = f2bf(s * src[j]);
  } else {
    const int tt = f - 96;
    const int row = tt*16 + r16;
    const float s = bnd1[row] * rsqrtf(bnd1[3*DM+row] + EPS);
    #pragma unroll
    for (int j=0;j<8;j++){
      const int k = kg + j;
      o8[j] = (k < 3) ? f2bf(s * Wd1[row*3 + k]) : (unsigned short)0;
    }
  }
  uint4 v;
  v.x = (uint32_t)o8[0] | ((uint32_t)o8[1]<<16);
  v.y = (uint32_t)o8[2] | ((uint32_t)o8[3]<<16);
  v.z = (uint32_t)o8[4] | ((uint32_t)o8[5]<<16);
  v.w = (uint32_t)o8[6] | ((uint32_t)o8[7]<<16);
  *reinterpret_cast<uint4*>(wfrag + (size_t)i*8) = v;
}

// ---------------------------------------------------------------- fused MFMA attention
// wave = one point (16 neighbors = 16 MFMA columns); 8 waves/block; PPW points per wave.
#define PPW 4
__global__ __launch_bounds__(512,1) void k_attn2(
    const float* __restrict__ pos, const float* __restrict__ q_ws,
    const float* __restrict__ k_ws, const float* __restrict__ v_ws,
    const int* __restrict__ idx_ws, const unsigned short* __restrict__ wfrag,
    const float* __restrict__ bnd1, const float* __restrict__ bnd2,
    const float* __restrict__ bng1, const float* __restrict__ bng2,
    float* __restrict__ res_ws){
  __shared__ __align__(16) unsigned short Wf[104*512];   // 104 KiB fragment store
  __shared__ __align__(16) unsigned short Hb[8][2048];   // 4 KiB/wave activation buf (B-layout, xor-swizzled)
  __shared__ float bnT[4][DM];

  const int t = threadIdx.x;
  for (int i = t; i < (104*512)/8; i += 512)
    reinterpret_cast<uint4*>(Wf)[i] = reinterpret_cast<const uint4*>(wfrag)[i];
  if (t < DM){
    const float* bp[4] = {bnd1, bnd2, bng1, bng2};
    #pragma unroll
    for (int s4=0;s4<4;s4++){
      const float g = bp[s4][t], be = bp[s4][DM+t], mn = bp[s4][2*DM+t], vr = bp[s4][3*DM+t];
      const float sc = g * rsqrtf(vr + EPS);
      bnT[s4][t] = be - mn*sc;           // scale folded into weights
    }
  }
  __syncthreads();

  const int w = t >> 6, l = t & 63;
  const int p = l & 15, g = l >> 4;
  unsigned short* hb = Hb[w];
  const int hwb = p*128 + ((g & 1) * 4);  // write base (ushort units), granule added per-tile

  #pragma unroll 1
  for (int pp = 0; pp < PPW; ++pp){
    const int gp = blockIdx.x*(8*PPW) + w*PPW + pp;
    const int b = gp >> 12, n = gp & (NN-1);
    const int mi = idx_ws[gp*KK + p];
    // ---- rel-pos B fragment (only k=0..2 nonzero -> lanes g==0)
    union { bf16x8 v; uint32_t u[4]; } bu;
    bu.u[0] = 0; bu.u[1] = 0; bu.u[2] = 0; bu.u[3] = 0;
    if (g == 0){
      const float* posb = pos + (size_t)b*3*NN;
      const float rx = posb[n]      - posb[mi];
      const float ry = posb[NN+n]   - posb[NN+mi];
      const float rz = posb[2*NN+n] - posb[2*NN+mi];
      bu.u[0] = pk2(rx, ry);
      bu.u[1] = pk2(rz, 0.f);
    }
    // ---- layer 1: h1 = lrelu(s1*Wd1 @ rel + t1) -> Hb
    #pragma unroll
    for (int tt=0; tt<8; ++tt){
      f32x4 acc = {0.f,0.f,0.f,0.f};
      const bf16x8 a = *reinterpret_cast<const bf16x8*>(&Wf[(96+tt)*512 + l*8]);
      acc = mfma16(a, bu.v, acc);
      const f32x4 sh = *reinterpret_cast<const f32x4*>(&bnT[0][tt*16 + g*4]);
      const int gw = tt*2 + (g>>1);
      uint2 hp;
      hp.x = pk2(lrelu(acc[0]+sh[0]), lrelu(acc[1]+sh[1]));
      hp.y = pk2(lrelu(acc[2]+sh[2]), lrelu(acc[3]+sh[3]));
      *reinterpret_cast<uint2*>(&hb[hwb + (gw^p)*8]) = hp;
    }
    // ---- layer 2: pe = lrelu(s2*Wd2 @ h1 + t2) (keep f32 in regs)
    float pe[32];
    {
      const bf16x8 b0 = *reinterpret_cast<const bf16x8*>(&hb[p*128 + ((0*4+g)^p)*8]);
      const bf16x8 b1 = *reinterpret_cast<const bf16x8*>(&hb[p*128 + ((1*4+g)^p)*8]);
      const bf16x8 b2 = *reinterpret_cast<const bf16x8*>(&hb[p*128 + ((2*4+g)^p)*8]);
      const bf16x8 b3 = *reinterpret_cast<const bf16x8*>(&hb[p*128 + ((3*4+g)^p)*8]);
      #pragma unroll
      for (int tt=0; tt<8; ++tt){
        f32x4 acc = {0.f,0.f,0.f,0.f};
        acc = mfma16(*reinterpret_cast<const bf16x8*>(&Wf[(0*32+tt*4+0)*512 + l*8]), b0, acc);
        acc = mfma16(*reinterpret_cast<const bf16x8*>(&Wf[(0*32+tt*4+1)*512 + l*8]), b1, acc);
        acc = mfma16(*reinterpret_cast<const bf16x8*>(&Wf[(0*32+tt*4+2)*512 + l*8]), b2, acc);
        acc = mfma16(*reinterpret_cast<const bf16x8*>(&Wf[(0*32+tt*4+3)*512 + l*8]), b3, acc);
        const f32x4 sh = *reinterpret_cast<const f32x4*>(&bnT[1][tt*16 + g*4]);
        pe[tt*4+0] = lrelu(acc[0]+sh[0]);
        pe[tt*4+1] = lrelu(acc[1]+sh[1]);
        pe[tt*4+2] = lrelu(acc[2]+sh[2]);
        pe[tt*4+3] = lrelu(acc[3]+sh[3]);
      }
    }
    // ---- aIn = q - k + pe -> Hb
    const float* qrow = q_ws + (size_t)gp*DM;
    const float* krow = k_ws + ((size_t)(b*NN) + mi)*DM;
    #pragma unroll
    for (int tt=0; tt<8; ++tt){
      const float4 qv = *reinterpret_cast<const float4*>(&qrow[tt*16 + g*4]);
      const float4 kv = *reinterpret_cast<const float4*>(&krow[tt*16 + g*4]);
      const int gw = tt*2 + (g>>1);
      uint2 hp;
      hp.x = pk2(qv.x - kv.x + pe[tt*4+0], qv.y - kv.y + pe[tt*4+1]);
      hp.y = pk2(qv.z - kv.z + pe[tt*4+2], qv.w - kv.w + pe[tt*4+3]);
      *reinterpret_cast<uint2*>(&hb[hwb + (gw^p)*8]) = hp;
    }
    // ---- layer 3: g1 = lrelu(s3*Wg1 @ aIn + t3) -> Hb
    {
      const bf16x8 b0 = *reinterpret_cast<const bf16x8*>(&hb[p*128 + ((0*4+g)^p)*8]);
      const bf16x8 b1 = *reinterpret_cast<const bf16x8*>(&hb[p*128 + ((1*4+g)^p)*8]);
      const bf16x8 b2 = *reinterpret_cast<const bf16x8*>(&hb[p*128 + ((2*4+g)^p)*8]);
      const bf16x8 b3 = *reinterpret_cast<const bf16x8*>(&hb[p*128 + ((3*4+g)^p)*8]);
      #pragma unroll
      for (int tt=0; tt<8; ++tt){
        f32x4 acc = {0.f,0.f,0.f,0.f};
        acc = mfma16(*reinterpret_cast<const bf16x8*>(&Wf[(1*32+tt*4+0)*512 + l*8]), b0, acc);
        acc = mfma16(*reinterpret_cast<const bf16x8*>(&Wf[(1*32+tt*4+1)*512 + l*8]), b1, acc);
        acc = mfma16(*reinterpret_cast<const bf16x8*>(&Wf[(1*32+tt*4+2)*512 + l*8]), b2, acc);
        acc = mfma16(*reinterpret_cast<const bf16x8*>(&Wf[(1*32+tt*4+3)*512 + l*8]), b3, acc);
        const f32x4 sh = *reinterpret_cast<const f32x4*>(&bnT[2][tt*16 + g*4]);
        const int gw = tt*2 + (g>>1);
        uint2 hp;
        hp.x = pk2(lrelu(acc[0]+sh[0]), lrelu(acc[1]+sh[1]));
        hp.y = pk2(lrelu(acc[2]+sh[2]), lrelu(acc[3]+sh[3]));
        *reinterpret_cast<uint2*>(&hb[hwb + (gw^p)*8]) = hp;
      }
    }
    // ---- layer 4: logits L = lrelu(s4*Wg2 @ g1 + t4) / 64
    float e[32];
    {
      const bf16x8 b0 = *reinterpret_cast<const bf16x8*>(&hb[p*128 + ((0*4+g)^p)*8]);
      const bf16x8 b1 = *reinterpret_cast<const bf16x8*>(&hb[p*128 + ((1*4+g)^p)*8]);
      const bf16x8 b2 = *reinterpret_cast<const bf16x8*>(&hb[p*128 + ((2*4+g)^p)*8]);
      const bf16x8 b3 = *reinterpret_cast<const bf16x8*>(&hb[p*128 + ((3*4+g)^p)*8]);
      #pragma unroll
      for (int tt=0; tt<8; ++tt){
        f32x4 acc = {0.f,0.f,0.f,0.f};
        acc = mfma16(*reinterpret_cast<const bf16x8*>(&Wf[(2*32+tt*4+0)*512 + l*8]), b0, acc);
        acc = mfma16(*reinterpret_cast<const bf16x8*>(&Wf[(2*32+tt*4+1)*512 + l*8]), b1, acc);
        acc = mfma16(*reinterpret_cast<const bf16x8*>(&Wf[(2*32+tt*4+2)*512 + l*8]), b2, acc);
        acc = mfma16(*reinterpret_cast<const bf16x8*>(&Wf[(2*32+tt*4+3)*512 + l*8]), b3, acc);
        const f32x4 sh = *reinterpret_cast<const f32x4*>(&bnT[3][tt*16 + g*4]);
        e[tt*4+0] = lrelu(acc[0]+sh[0]) * 0.015625f;
        e[tt*4+1] = lrelu(acc[1]+sh[1]) * 0.015625f;
        e[tt*4+2] = lrelu(acc[2]+sh[2]) * 0.015625f;
        e[tt*4+3] = lrelu(acc[3]+sh[3]) * 0.015625f;
      }
    }
    // ---- softmax over neighbors (cols, lanes sharing g): shared safe max
    float m = e[0];
    #pragma unroll
    for (int i=1;i<32;i++) m = fmaxf(m, e[i]);
    #pragma unroll
    for (int mk=1; mk<16; mk<<=1) m = fmaxf(m, sx16(m, mk));
    #pragma unroll
    for (int i=0;i<32;i++) e[i] = __expf(e[i] - m);
    // ---- weighted reduce of (v + pe) over neighbors, per channel
    const float* vrow = v_ws + ((size_t)(b*NN) + mi)*DM;
    #pragma unroll
    for (int tt=0; tt<8; ++tt){
      const float4 vv = *reinterpret_cast<const float4*>(&vrow[tt*16 + g*4]);
      #pragma unroll
      for (int r=0;r<4;r++){
        const int i = tt*4 + r;
        const float vr4 = (r==0?vv.x : r==1?vv.y : r==2?vv.z : vv.w);
        float num = e[i] * (vr4 + pe[i]);
        float den = e[i];
        #pragma unroll
        for (int mk=1; mk<16; mk<<=1){ num += sx16(num, mk); den += sx16(den, mk); }
        pe[i] = num * __builtin_amdgcn_rcpf(den);
      }
    }
    if (p == 0){
      #pragma unroll
      for (int tt=0; tt<8; ++tt){
        float4 o;
        o.x = pe[tt*4+0]; o.y = pe[tt*4+1]; o.z = pe[tt*4+2]; o.w = pe[tt*4+3];
        *reinterpret_cast<float4*>(&res_ws[(size_t)gp*DM + tt*16 + g*4]) = o;
      }
    }
  }
}

// ---------------------------------------------------------------- out = lrelu(bn2(W2@res)) + feats
__global__ __launch_bounds__(256) void k_out(const float* __restrict__ res_ws,
                                             const float* __restrict__ W2,
                                             const float* __restrict__ bn2,
                                             const float* __restrict__ feats,
                                             float* __restrict__ out){
  __shared__ float W2s[DP][DM+4];
  __shared__ float rt[128][DM+4];
  __shared__ float ob[DP][132];
  __shared__ float bS[DP], bT[DP];
  const int t = threadIdx.x;
  const int b = blockIdx.x >> 5;
  const int n0 = (blockIdx.x & 31) * 128;
  for (int i=t; i<DP*DM; i+=256){ W2s[i>>7][i&127] = W2[i]; }
  if (t < DP){
    float g=bn2[t], be=bn2[DP+t], mn=bn2[2*DP+t], vr=bn2[3*DP+t];
    float s = g*rsqrtf(vr+EPS); bS[t]=s; bT[t]=be-mn*s;
  }
  for (int i=t; i<128*DM; i+=256){
    const int j=i>>7, c=i&127;
    rt[j][c] = res_ws[((size_t)(b*NN)+n0+j)*DM + c];
  }
  __syncthreads();
  const int j = t>>1, cq = t&1;
  float acc[32];
  #pragma unroll
  for (int i=0;i<32;i++) acc[i]=0.f;
  for (int c=0;c<DM;c+=4){
    const float4 rv = *reinterpret_cast<const float4*>(&rt[j][c]);
    #pragma unroll
    for (int i=0;i<32;i++){
      const float4 wv = *reinterpret_cast<const float4*>(&W2s[cq+2*i][c]);
      acc[i] += wv.x*rv.x + wv.y*rv.y + wv.z*rv.z + wv.w*rv.w;
    }
  }
  #pragma unroll
  for (int i=0;i<32;i++) ob[cq+2*i][j] = acc[i];
  __syncthreads();
  for (int i=t; i<DP*128; i+=256){
    const int ch=i>>7, jj=i&127;
    const size_t o = (size_t)b*DP*NN + (size_t)ch*NN + n0 + jj;
    out[o] = lrelu(ob[ch][jj]*bS[ch] + bT[ch]) + feats[o];
  }
}

// ----------------------------------------------------------------
extern "C" void kernel_launch(void* const* d_in, const int* in_sizes, int n_in,
                              void* d_out, int out_size, void* d_ws, size_t ws_size,
                              hipStream_t stream) {
  const float* feats = (const float*)d_in[0];
  const float* pos   = (const float*)d_in[1];
  const float* W1    = (const float*)d_in[2];
  const float* bn1   = (const float*)d_in[3];
  const float* W2    = (const float*)d_in[4];
  const float* bn2   = (const float*)d_in[5];
  const float* Wq    = (const float*)d_in[6];
  const float* Wk    = (const float*)d_in[7];
  const float* Wv    = (const float*)d_in[8];
  const float* Wd1   = (const float*)d_in[9];
  const float* bnd1  = (const float*)d_in[10];
  const float* Wd2   = (const float*)d_in[11];
  const float* bnd2  = (const float*)d_in[12];
  const float* Wg1   = (const float*)d_in[13];
  const float* bng1  = (const float*)d_in[14];
  const float* Wg2   = (const float*)d_in[15];
  const float* bng2  = (const float*)d_in[16];
  float* out = (float*)d_out;

  float* ws   = (float*)d_ws;
  float* q_ws = ws;
  float* k_ws = q_ws + (size_t)NB*NN*DM;
  float* v_ws = k_ws + (size_t)NB*NN*DM;
  float* x_ws = v_ws + (size_t)NB*NN*DM;      // reused as res_ws after k_qkv
  float* sqn  = x_ws + (size_t)NB*NN*DM;
  int*   idx  = (int*)(sqn + (size_t)NB*NN);
  unsigned short* wfrag = (unsigned short*)(idx + (size_t)NB*NN*KK);

  k_wprep <<<26, 256, 0, stream>>>(Wd1, bnd1, Wd2, bnd2, Wg1, bng1, Wg2, bng2, wfrag);
  k_sqnorm<<<(NB*NN)/256, 256, 0, stream>>>(feats, sqn);
  k_x     <<<NB*(NN/64), 256, 0, stream>>>(feats, W1, bn1, x_ws);
  k_qkv   <<<NB*(NN/64), 256, 0, stream>>>(x_ws, Wq, Wk, Wv, q_ws, k_ws, v_ws);
  k_knn   <<<NB*(NN/32), 256, 0, stream>>>(feats, sqn, idx);
  k_attn2 <<<(NB*NN)/(8*PPW), 512, 0, stream>>>(pos, q_ws, k_ws, v_ws, idx, wfrag,
                                                bnd1, bnd2, bng1, bng2, x_ws);
  k_out   <<<NB*(NN/128), 256, 0, stream>>>(x_ws, W2, bn2, feats, out);
}

// Round 4
// 1314.065 us; speedup vs baseline: 2.9296x; 1.3441x over previous
//
#include <hip/hip_runtime.h>
#include <cstdint>
#include <cstddef>

#define NB 4
#define NN 4096
#define KK 16
#define DP 64
#define DM 128
#define EPS 1e-5f

typedef __attribute__((ext_vector_type(8))) short bf16x8;
typedef __attribute__((ext_vector_type(4))) float f32x4;

__device__ __forceinline__ float lrelu(float x){ return x >= 0.f ? x : 0.2f*x; }

__device__ __forceinline__ unsigned short f2bf(float x){
  union { float f; uint32_t u; } a; a.f = x;
  return (unsigned short)((a.u + 0x7fffu + ((a.u >> 16) & 1u)) >> 16);
}
__device__ __forceinline__ float bf2f(unsigned short h){
  union { uint32_t u; float f; } a; a.u = ((uint32_t)h) << 16; return a.f;
}
__device__ __forceinline__ uint32_t pk2(float a, float b){
  return (uint32_t)f2bf(a) | ((uint32_t)f2bf(b) << 16);
}

__device__ __forceinline__ f32x4 mfma16(bf16x8 a, bf16x8 b, f32x4 c){
  return __builtin_amdgcn_mfma_f32_16x16x32_bf16(a, b, c, 0, 0, 0);
}
__device__ __forceinline__ float sx16(float v, int m){ return __shfl_xor(v, m, 16); }

// ---------------------------------------------------------------- sq norms
__global__ __launch_bounds__(256) void k_sqnorm(const float* __restrict__ feats,
                                                float* __restrict__ sqn){
  const int i = blockIdx.x*256 + threadIdx.x;
  const int b = i >> 12, n = i & (NN-1);
  const float* f = feats + (size_t)b*DP*NN + n;
  float s = 0.f;
  #pragma unroll
  for (int c=0;c<DP;c++){ const float v = f[(size_t)c*NN]; s += v*v; }
  sqn[i] = s;
}

// ---------------------------------------------------------------- feats -> bf16 hi/lo MFMA fragments + point-major f32 copy
__global__ __launch_bounds__(256) void k_fprep(const float* __restrict__ feats,
                                               unsigned short* __restrict__ cfrag,
                                               unsigned short* __restrict__ qfrag,
                                               float* __restrict__ fpm){
  __shared__ float ft[DP][65];
  const int t = threadIdx.x;
  const int b = blockIdx.x >> 6;
  const int n0 = (blockIdx.x & 63) * 64;
  for (int i=t; i<DP*64; i+=256){
    const int dim = i >> 6, pt = i & 63;
    ft[dim][pt] = feats[(size_t)b*DP*NN + (size_t)dim*NN + n0 + pt];
  }
  __syncthreads();
  // point-major f32 copy (coalesced refine reads)
  for (int i=t; i<64*DP; i+=256){
    const int pt = i >> 6, dim = i & 63;
    fpm[((size_t)(b*NN) + n0 + pt)*DP + dim] = ft[dim][pt];
  }
  #pragma unroll
  for (int v = t; v < 1024; v += 256){
    const int l = v & 63, hl = (v>>6)&1, ks = (v>>7)&1, ntl = v>>8;
    const int ptl = ntl*16 + (l&15);
    const int d0 = ks*32 + (l>>4)*8;
    unsigned short qo[8], co[8];
    #pragma unroll
    for (int j=0;j<8;j++){
      const float x = ft[d0+j][ptl];
      const unsigned short qh = f2bf(x);
      const float y = -2.f*x;
      const unsigned short ch = f2bf(y);
      qo[j] = hl ? f2bf(x - bf2f(qh)) : qh;
      co[j] = hl ? f2bf(y - bf2f(ch)) : ch;
    }
    const int nt = (n0 >> 4) + ntl;
    const size_t off = ((size_t)((b*256 + nt)*4 + ks*2 + hl))*512 + l*8;
    uint4 qv, cv;
    qv.x = (uint32_t)qo[0] | ((uint32_t)qo[1]<<16);
    qv.y = (uint32_t)qo[2] | ((uint32_t)qo[3]<<16);
    qv.z = (uint32_t)qo[4] | ((uint32_t)qo[5]<<16);
    qv.w = (uint32_t)qo[6] | ((uint32_t)qo[7]<<16);
    cv.x = (uint32_t)co[0] | ((uint32_t)co[1]<<16);
    cv.y = (uint32_t)co[2] | ((uint32_t)co[3]<<16);
    cv.z = (uint32_t)co[4] | ((uint32_t)co[5]<<16);
    cv.w = (uint32_t)co[6] | ((uint32_t)co[7]<<16);
    *reinterpret_cast<uint4*>(qfrag + off) = qv;
    *reinterpret_cast<uint4*>(cfrag + off) = cv;
  }
}

// ---------------------------------------------------------------- MFMA kNN: approx top-32 candidates per query
__global__ __launch_bounds__(256) void k_knn2(const unsigned short* __restrict__ cfrag,
                                              const unsigned short* __restrict__ qfrag,
                                              const float* __restrict__ sqn,
                                              int* __restrict__ cand){
  const int t = threadIdx.x, w = t >> 6, l = t & 63, g = l >> 4;
  const int b = blockIdx.x >> 6;
  const int qt = (blockIdx.x & 63)*4 + w;

  bf16x8 qf00, qf01, qf10, qf11;
  {
    const unsigned short* qb = qfrag + ((size_t)(b*256 + qt))*2048 + l*8;
    qf00 = *reinterpret_cast<const bf16x8*>(qb);
    qf01 = *reinterpret_cast<const bf16x8*>(qb + 512);
    qf10 = *reinterpret_cast<const bf16x8*>(qb + 1024);
    qf11 = *reinterpret_cast<const bf16x8*>(qb + 1536);
  }
  const unsigned short* cb = cfrag + ((size_t)(b*256))*2048 + l*8;

  float dd[16]; int ii[16];
  #pragma unroll
  for (int s=0;s<16;s++){ dd[s]=3.4e38f; ii[s]=0; }
  float dmax = 3.4e38f;

  bf16x8 c00 = *reinterpret_cast<const bf16x8*>(cb);
  bf16x8 c01 = *reinterpret_cast<const bf16x8*>(cb + 512);
  bf16x8 c10 = *reinterpret_cast<const bf16x8*>(cb + 1024);
  bf16x8 c11 = *reinterpret_cast<const bf16x8*>(cb + 1536);

  const float* sqb = sqn + b*NN + g*4;

  #pragma unroll 1
  for (int ct=0; ct<256; ++ct){
    bf16x8 n00, n01, n10, n11;
    if (ct < 255){
      const unsigned short* nb_ = cb + (size_t)(ct+1)*2048;
      n00 = *reinterpret_cast<const bf16x8*>(nb_);
      n01 = *reinterpret_cast<const bf16x8*>(nb_ + 512);
      n10 = *reinterpret_cast<const bf16x8*>(nb_ + 1024);
      n11 = *reinterpret_cast<const bf16x8*>(nb_ + 1536);
    }
    f32x4 acc = {0.f,0.f,0.f,0.f};
    acc = mfma16(c00, qf00, acc);
    acc = mfma16(c10, qf10, acc);
    acc = mfma16(c00, qf01, acc);
    acc = mfma16(c01, qf00, acc);
    acc = mfma16(c10, qf11, acc);
    acc = mfma16(c11, qf10, acc);
    const float4 sq4 = *reinterpret_cast<const float4*>(&sqb[ct*16]);
    const float d0 = acc[0] + sq4.x;
    const float d1 = acc[1] + sq4.y;
    const float d2 = acc[2] + sq4.z;
    const float d3 = acc[3] + sq4.w;
    const float mn = fminf(fminf(d0,d1), fminf(d2,d3));
    if (mn < dmax){
      const int cbase = ct*16 + g*4;
      float dv[4] = {d0,d1,d2,d3};
      #pragma unroll
      for (int u=0;u<4;u++){
        if (dv[u] < dmax){
          bool done=false;
          #pragma unroll
          for (int s=0;s<16;s++){
            if (!done && dd[s]==dmax){ dd[s]=dv[u]; ii[s]=cbase+u; done=true; }
          }
          dmax = dd[0];
          #pragma unroll
          for (int s=1;s<16;s++) dmax = fmaxf(dmax, dd[s]);
        }
      }
    }
    c00 = n00; c01 = n01; c10 = n10; c11 = n11;
  }

  // ---- merge across the 4 g-lanes per query: 32 extraction rounds
  const int q = qt*16 + (l & 15);
  int* op = cand + ((size_t)(b*NN) + q)*32;
  #pragma unroll 1
  for (int r=0; r<32; ++r){
    float bd = dd[0]; int bi = ii[0];
    #pragma unroll
    for (int s=1;s<16;s++){
      if (dd[s] < bd){ bd = dd[s]; bi = ii[s]; }
    }
    const int mi0 = bi;
    float od; int oi;
    od = __shfl_xor(bd, 16); oi = __shfl_xor(bi, 16);
    if (od < bd){ bd = od; bi = oi; }
    od = __shfl_xor(bd, 32); oi = __shfl_xor(bi, 32);
    if (od < bd){ bd = od; bi = oi; }
    const bool win = (bi == mi0);
    #pragma unroll
    for (int s=0;s<16;s++){
      if (win && ii[s]==bi) dd[s] = 3.4e38f;
    }
    if (g == 0) op[r] = bi;
  }
}

// ---------------------------------------------------------------- exact f32 refine: top-16 set from 32 candidates
__global__ __launch_bounds__(256) void k_refine(const float* __restrict__ fpm,
                                                const float* __restrict__ sqn,
                                                const int* __restrict__ cand,
                                                int* __restrict__ idx_ws){
  const int t = threadIdx.x, w = t >> 6, l = t & 63;
  const int q = blockIdx.x*4 + w;           // global point id b*NN+n
  const int b = q >> 12;
  const int c = l & 31, h = l >> 5;
  const int mi = cand[(size_t)q*32 + c];
  const float* qv = fpm + (size_t)q*DP + h*32;
  const float* cv = fpm + ((size_t)(b*NN) + mi)*DP + h*32;
  float dot = 0.f;
  #pragma unroll
  for (int d=0; d<32; d+=4){
    const float4 a = *reinterpret_cast<const float4*>(&qv[d]);
    const float4 x = *reinterpret_cast<const float4*>(&cv[d]);
    dot += a.x*x.x; dot += a.y*x.y; dot += a.z*x.z; dot += a.w*x.w;
  }
  dot += __shfl_xor(dot, 32);
  const float dist = sqn[q] + sqn[b*NN + mi] - 2.f*dot;
  int rank = 0;
  #pragma unroll
  for (int j=0; j<32; j++){
    const float dj = __shfl(dist, j);
    const int   ij = __shfl(mi,  j);
    rank += (dj < dist || (dj == dist && ij < mi)) ? 1 : 0;
  }
  if (h == 0 && rank < KK) idx_ws[(size_t)q*KK + rank] = mi;
}

// ---------------------------------------------------------------- x = lrelu(bn1(W1@feats)), point-major out
__global__ __launch_bounds__(256) void k_x(const float* __restrict__ feats,
                                           const float* __restrict__ W1,
                                           const float* __restrict__ bn1,
                                           float* __restrict__ x_ws){
  __shared__ float W1s[DM][DP+1];
  __shared__ float ft[DP][64];
  __shared__ float bS[DM], bT[DM];
  const int t = threadIdx.x;
  const int b = blockIdx.x >> 6;
  const int n0 = (blockIdx.x & 63) * 64;
  for (int i=t; i<DM*DP; i+=256){ W1s[i>>6][i&63] = W1[i]; }
  if (t < DM){
    float g = bn1[t], be = bn1[DM+t], mn = bn1[2*DM+t], vr = bn1[3*DM+t];
    float s = g*rsqrtf(vr+EPS); bS[t]=s; bT[t]=be-mn*s;
  }
  for (int i=t; i<DP*64; i+=256){
    const int c = i>>6, j = i&63;
    ft[c][j] = feats[(size_t)b*DP*NN + (size_t)c*NN + n0 + j];
  }
  __syncthreads();
  const int j = t >> 2, cq = t & 3;
  float acc[32];
  #pragma unroll
  for (int i=0;i<32;i++) acc[i]=0.f;
  for (int c=0;c<DP;c++){
    const float fv = ft[c][j];
    #pragma unroll
    for (int i=0;i<32;i++) acc[i] += W1s[cq+4*i][c]*fv;
  }
  float* xo = x_ws + ((size_t)(b*NN) + n0 + j)*DM;
  #pragma unroll
  for (int i=0;i<32;i++){
    const int ch = cq + 4*i;
    xo[ch] = lrelu(acc[i]*bS[ch] + bT[ch]);
  }
}

// ---------------------------------------------------------------- q/k/v = W{q,k,v} @ x, point-major out
__global__ __launch_bounds__(256) void k_qkv(const float* __restrict__ x_ws,
                                             const float* __restrict__ Wq,
                                             const float* __restrict__ Wk,
                                             const float* __restrict__ Wv,
                                             float* __restrict__ q_ws,
                                             float* __restrict__ k_ws,
                                             float* __restrict__ v_ws){
  __shared__ float Ws[DM][DM+4];
  __shared__ float xt[64][DM+4];
  const int t = threadIdx.x;
  const int b = blockIdx.x >> 6;
  const int n0 = (blockIdx.x & 63) * 64;
  for (int i=t; i<64*DM; i+=256){
    const int j = i>>7, c = i&127;
    xt[j][c] = x_ws[((size_t)(b*NN) + n0 + j)*DM + c];
  }
  const float* Wp[3] = {Wq, Wk, Wv};
  float* Op[3] = {q_ws, k_ws, v_ws};
  for (int wi=0; wi<3; wi++){
    __syncthreads();
    for (int i=t; i<DM*DM; i+=256){ Ws[i>>7][i&127] = Wp[wi][i]; }
    __syncthreads();
    const int j = t>>2, cq = t&3;
    float acc[32];
    #pragma unroll
    for (int i=0;i<32;i++) acc[i]=0.f;
    for (int c=0;c<DM;c+=4){
      const float4 xv = *reinterpret_cast<const float4*>(&xt[j][c]);
      #pragma unroll
      for (int i=0;i<32;i++){
        const float4 wv = *reinterpret_cast<const float4*>(&Ws[cq+4*i][c]);
        acc[i] += wv.x*xv.x + wv.y*xv.y + wv.z*xv.z + wv.w*xv.w;
      }
    }
    float* op = Op[wi] + ((size_t)(b*NN) + n0 + j)*DM;
    #pragma unroll
    for (int i=0;i<32;i++) op[cq+4*i] = acc[i];
  }
}

// ---------------------------------------------------------------- weight prep: bf16 MFMA fragments, bn-scale folded
__global__ __launch_bounds__(256) void k_wprep(
    const float* __restrict__ Wd1, const float* __restrict__ bnd1,
    const float* __restrict__ Wd2, const float* __restrict__ bnd2,
    const float* __restrict__ Wg1, const float* __restrict__ bng1,
    const float* __restrict__ Wg2, const float* __restrict__ bng2,
    unsigned short* __restrict__ wfrag){
  const int i = blockIdx.x*256 + threadIdx.x;
  if (i >= 104*64) return;
  const int f = i >> 6, l = i & 63;
  const int r16 = l & 15, kg = (l >> 4) * 8;
  unsigned short o8[8];
  if (f < 96){
    const int mat = f >> 5, tt = (f >> 2) & 7, ks = f & 3;
    const float* W; const float* bn;
    if (mat == 0){ W = Wd2; bn = bnd2; }
    else if (mat == 1){ W = Wg1; bn = bng1; }
    else { W = Wg2; bn = bng2; }
    const int row = tt*16 + r16;
    const float s = bn[row] * rsqrtf(bn[3*DM+row] + EPS);
    const float* src = W + (size_t)row*DM + ks*32 + kg;
    #pragma unroll
    for (int j=0;j<8;j++) o8[j] = f2bf(s * src[j]);
  } else {
    const int tt = f - 96;
    const int row = tt*16 + r16;
    const float s = bnd1[row] * rsqrtf(bnd1[3*DM+row] + EPS);
    #pragma unroll
    for (int j=0;j<8;j++){
      const int k = kg + j;
      o8[j] = (k < 3) ? f2bf(s * Wd1[row*3 + k]) : (unsigned short)0;
    }
  }
  uint4 v;
  v.x = (uint32_t)o8[0] | ((uint32_t)o8[1]<<16);
  v.y = (uint32_t)o8[2] | ((uint32_t)o8[3]<<16);
  v.z = (uint32_t)o8[4] | ((uint32_t)o8[5]<<16);
  v.w = (uint32_t)o8[6] | ((uint32_t)o8[7]<<16);
  *reinterpret_cast<uint4*>(wfrag + (size_t)i*8) = v;
}

// ---------------------------------------------------------------- fused MFMA attention
#define PPW 4
__global__ __launch_bounds__(512,1) void k_attn2(
    const float* __restrict__ pos, const float* __restrict__ q_ws,
    const float* __restrict__ k_ws, const float* __restrict__ v_ws,
    const int* __restrict__ idx_ws, const unsigned short* __restrict__ wfrag,
    const float* __restrict__ bnd1, const float* __restrict__ bnd2,
    const float* __restrict__ bng1, const float* __restrict__ bng2,
    float* __restrict__ res_ws){
  __shared__ __align__(16) unsigned short Wf[104*512];
  __shared__ __align__(16) unsigned short Hb[8][2048];
  __shared__ float bnT[4][DM];

  const int t = threadIdx.x;
  for (int i = t; i < (104*512)/8; i += 512)
    reinterpret_cast<uint4*>(Wf)[i] = reinterpret_cast<const uint4*>(wfrag)[i];
  if (t < DM){
    const float* bp[4] = {bnd1, bnd2, bng1, bng2};
    #pragma unroll
    for (int s4=0;s4<4;s4++){
      const float g = bp[s4][t], be = bp[s4][DM+t], mn = bp[s4][2*DM+t], vr = bp[s4][3*DM+t];
      const float sc = g * rsqrtf(vr + EPS);
      bnT[s4][t] = be - mn*sc;
    }
  }
  __syncthreads();

  const int w = t >> 6, l = t & 63;
  const int p = l & 15, g = l >> 4;
  unsigned short* hb = Hb[w];
  const int hwb = p*128 + ((g & 1) * 4);

  #pragma unroll 1
  for (int pp = 0; pp < PPW; ++pp){
    const int gp = blockIdx.x*(8*PPW) + w*PPW + pp;
    const int b = gp >> 12, n = gp & (NN-1);
    const int mi = idx_ws[gp*KK + p];
    union { bf16x8 v; uint32_t u[4]; } bu;
    bu.u[0] = 0; bu.u[1] = 0; bu.u[2] = 0; bu.u[3] = 0;
    if (g == 0){
      const float* posb = pos + (size_t)b*3*NN;
      const float rx = posb[n]      - posb[mi];
      const float ry = posb[NN+n]   - posb[NN+mi];
      const float rz = posb[2*NN+n] - posb[2*NN+mi];
      bu.u[0] = pk2(rx, ry);
      bu.u[1] = pk2(rz, 0.f);
    }
    #pragma unroll
    for (int tt=0; tt<8; ++tt){
      f32x4 acc = {0.f,0.f,0.f,0.f};
      const bf16x8 a = *reinterpret_cast<const bf16x8*>(&Wf[(96+tt)*512 + l*8]);
      acc = mfma16(a, bu.v, acc);
      const f32x4 sh = *reinterpret_cast<const f32x4*>(&bnT[0][tt*16 + g*4]);
      const int gw = tt*2 + (g>>1);
      uint2 hp;
      hp.x = pk2(lrelu(acc[0]+sh[0]), lrelu(acc[1]+sh[1]));
      hp.y = pk2(lrelu(acc[2]+sh[2]), lrelu(acc[3]+sh[3]));
      *reinterpret_cast<uint2*>(&hb[hwb + (gw^p)*8]) = hp;
    }
    float pe[32];
    {
      const bf16x8 b0 = *reinterpret_cast<const bf16x8*>(&hb[p*128 + ((0*4+g)^p)*8]);
      const bf16x8 b1 = *reinterpret_cast<const bf16x8*>(&hb[p*128 + ((1*4+g)^p)*8]);
      const bf16x8 b2 = *reinterpret_cast<const bf16x8*>(&hb[p*128 + ((2*4+g)^p)*8]);
      const bf16x8 b3 = *reinterpret_cast<const bf16x8*>(&hb[p*128 + ((3*4+g)^p)*8]);
      #pragma unroll
      for (int tt=0; tt<8; ++tt){
        f32x4 acc = {0.f,0.f,0.f,0.f};
        acc = mfma16(*reinterpret_cast<const bf16x8*>(&Wf[(0*32+tt*4+0)*512 + l*8]), b0, acc);
        acc = mfma16(*reinterpret_cast<const bf16x8*>(&Wf[(0*32+tt*4+1)*512 + l*8]), b1, acc);
        acc = mfma16(*reinterpret_cast<const bf16x8*>(&Wf[(0*32+tt*4+2)*512 + l*8]), b2, acc);
        acc = mfma16(*reinterpret_cast<const bf16x8*>(&Wf[(0*32+tt*4+3)*512 + l*8]), b3, acc);
        const f32x4 sh = *reinterpret_cast<const f32x4*>(&bnT[1][tt*16 + g*4]);
        pe[tt*4+0] = lrelu(acc[0]+sh[0]);
        pe[tt*4+1] = lrelu(acc[1]+sh[1]);
        pe[tt*4+2] = lrelu(acc[2]+sh[2]);
        pe[tt*4+3] = lrelu(acc[3]+sh[3]);
      }
    }
    const float* qrow = q_ws + (size_t)gp*DM;
    const float* krow = k_ws + ((size_t)(b*NN) + mi)*DM;
    #pragma unroll
    for (int tt=0; tt<8; ++tt){
      const float4 qv = *reinterpret_cast<const float4*>(&qrow[tt*16 + g*4]);
      const float4 kv = *reinterpret_cast<const float4*>(&krow[tt*16 + g*4]);
      const int gw = tt*2 + (g>>1);
      uint2 hp;
      hp.x = pk2(qv.x - kv.x + pe[tt*4+0], qv.y - kv.y + pe[tt*4+1]);
      hp.y = pk2(qv.z - kv.z + pe[tt*4+2], qv.w - kv.w + pe[tt*4+3]);
      *reinterpret_cast<uint2*>(&hb[hwb + (gw^p)*8]) = hp;
    }
    {
      const bf16x8 b0 = *reinterpret_cast<const bf16x8*>(&hb[p*128 + ((0*4+g)^p)*8]);
      const bf16x8 b1 = *reinterpret_cast<const bf16x8*>(&hb[p*128 + ((1*4+g)^p)*8]);
      const bf16x8 b2 = *reinterpret_cast<const bf16x8*>(&hb[p*128 + ((2*4+g)^p)*8]);
      const bf16x8 b3 = *reinterpret_cast<const bf16x8*>(&hb[p*128 + ((3*4+g)^p)*8]);
      #pragma unroll
      for (int tt=0; tt<8; ++tt){
        f32x4 acc = {0.f,0.f,0.f,0.f};
        acc = mfma16(*reinterpret_cast<const bf16x8*>(&Wf[(1*32+tt*4+0)*512 + l*8]), b0, acc);
        acc = mfma16(*reinterpret_cast<const bf16x8*>(&Wf[(1*32+tt*4+1)*512 + l*8]), b1, acc);
        acc = mfma16(*reinterpret_cast<const bf16x8*>(&Wf[(1*32+tt*4+2)*512 + l*8]), b2, acc);
        acc = mfma16(*reinterpret_cast<const bf16x8*>(&Wf[(1*32+tt*4+3)*512 + l*8]), b3, acc);
        const f32x4 sh = *reinterpret_cast<const f32x4*>(&bnT[2][tt*16 + g*4]);
        const int gw = tt*2 + (g>>1);
        uint2 hp;
        hp.x = pk2(lrelu(acc[0]+sh[0]), lrelu(acc[1]+sh[1]));
        hp.y = pk2(lrelu(acc[2]+sh[2]), lrelu(acc[3]+sh[3]));
        *reinterpret_cast<uint2*>(&hb[hwb + (gw^p)*8]) = hp;
      }
    }
    float e[32];
    {
      const bf16x8 b0 = *reinterpret_cast<const bf16x8*>(&hb[p*128 + ((0*4+g)^p)*8]);
      const bf16x8 b1 = *reinterpret_cast<const bf16x8*>(&hb[p*128 + ((1*4+g)^p)*8]);
      const bf16x8 b2 = *reinterpret_cast<const bf16x8*>(&hb[p*128 + ((2*4+g)^p)*8]);
      const bf16x8 b3 = *reinterpret_cast<const bf16x8*>(&hb[p*128 + ((3*4+g)^p)*8]);
      #pragma unroll
      for (int tt=0; tt<8; ++tt){
        f32x4 acc = {0.f,0.f,0.f,0.f};
        acc = mfma16(*reinterpret_cast<const bf16x8*>(&Wf[(2*32+tt*4+0)*512 + l*8]), b0, acc);
        acc = mfma16(*reinterpret_cast<const bf16x8*>(&Wf[(2*32+tt*4+1)*512 + l*8]), b1, acc);
        acc = mfma16(*reinterpret_cast<const bf16x8*>(&Wf[(2*32+tt*4+2)*512 + l*8]), b2, acc);
        acc = mfma16(*reinterpret_cast<const bf16x8*>(&Wf[(2*32+tt*4+3)*512 + l*8]), b3, acc);
        const f32x4 sh = *reinterpret_cast<const f32x4*>(&bnT[3][tt*16 + g*4]);
        e[tt*4+0] = lrelu(acc[0]+sh[0]) * 0.015625f;
        e[tt*4+1] = lrelu(acc[1]+sh[1]) * 0.015625f;
        e[tt*4+2] = lrelu(acc[2]+sh[2]) * 0.015625f;
        e[tt*4+3] = lrelu(acc[3]+sh[3]) * 0.015625f;
      }
    }
    float m = e[0];
    #pragma unroll
    for (int i=1;i<32;i++) m = fmaxf(m, e[i]);
    #pragma unroll
    for (int mk=1; mk<16; mk<<=1) m = fmaxf(m, sx16(m, mk));
    #pragma unroll
    for (int i=0;i<32;i++) e[i] = __expf(e[i] - m);
    const float* vrow = v_ws + ((size_t)(b*NN) + mi)*DM;
    #pragma unroll
    for (int tt=0; tt<8; ++tt){
      const float4 vv = *reinterpret_cast<const float4*>(&vrow[tt*16 + g*4]);
      #pragma unroll
      for (int r=0;r<4;r++){
        const int i = tt*4 + r;
        const float vr4 = (r==0?vv.x : r==1?vv.y : r==2?vv.z : vv.w);
        float num = e[i] * (vr4 + pe[i]);
        float den = e[i];
        #pragma unroll
        for (int mk=1; mk<16; mk<<=1){ num += sx16(num, mk); den += sx16(den, mk); }
        pe[i] = num * __builtin_amdgcn_rcpf(den);
      }
    }
    if (p == 0){
      #pragma unroll
      for (int tt=0; tt<8; ++tt){
        float4 o;
        o.x = pe[tt*4+0]; o.y = pe[tt*4+1]; o.z = pe[tt*4+2]; o.w = pe[tt*4+3];
        *reinterpret_cast<float4*>(&res_ws[(size_t)gp*DM + tt*16 + g*4]) = o;
      }
    }
  }
}

// ---------------------------------------------------------------- out = lrelu(bn2(W2@res)) + feats
__global__ __launch_bounds__(256) void k_out(const float* __restrict__ res_ws,
                                             const float* __restrict__ W2,
                                             const float* __restrict__ bn2,
                                             const float* __restrict__ feats,
                                             float* __restrict__ out){
  __shared__ float W2s[DP][DM+4];
  __shared__ float rt[128][DM+4];
  __shared__ float ob[DP][132];
  __shared__ float bS[DP], bT[DP];
  const int t = threadIdx.x;
  const int b = blockIdx.x >> 5;
  const int n0 = (blockIdx.x & 31) * 128;
  for (int i=t; i<DP*DM; i+=256){ W2s[i>>7][i&127] = W2[i]; }
  if (t < DP){
    float g=bn2[t], be=bn2[DP+t], mn=bn2[2*DP+t], vr=bn2[3*DP+t];
    float s = g*rsqrtf(vr+EPS); bS[t]=s; bT[t]=be-mn*s;
  }
  for (int i=t; i<128*DM; i+=256){
    const int j=i>>7, c=i&127;
    rt[j][c] = res_ws[((size_t)(b*NN)+n0+j)*DM + c];
  }
  __syncthreads();
  const int j = t>>1, cq = t&1;
  float acc[32];
  #pragma unroll
  for (int i=0;i<32;i++) acc[i]=0.f;
  for (int c=0;c<DM;c+=4){
    const float4 rv = *reinterpret_cast<const float4*>(&rt[j][c]);
    #pragma unroll
    for (int i=0;i<32;i++){
      const float4 wv = *reinterpret_cast<const float4*>(&W2s[cq+2*i][c]);
      acc[i] += wv.x*rv.x + wv.y*rv.y + wv.z*rv.z + wv.w*rv.w;
    }
  }
  #pragma unroll
  for (int i=0;i<32;i++) ob[cq+2*i][j] = acc[i];
  __syncthreads();
  for (int i=t; i<DP*128; i+=256){
    const int ch=i>>7, jj=i&127;
    const size_t o = (size_t)b*DP*NN + (size_t)ch*NN + n0 + jj;
    out[o] = lrelu(ob[ch][jj]*bS[ch] + bT[ch]) + feats[o];
  }
}

// ----------------------------------------------------------------
extern "C" void kernel_launch(void* const* d_in, const int* in_sizes, int n_in,
                              void* d_out, int out_size, void* d_ws, size_t ws_size,
                              hipStream_t stream) {
  const float* feats = (const float*)d_in[0];
  const float* pos   = (const float*)d_in[1];
  const float* W1    = (const float*)d_in[2];
  const float* bn1   = (const float*)d_in[3];
  const float* W2    = (const float*)d_in[4];
  const float* bn2   = (const float*)d_in[5];
  const float* Wq    = (const float*)d_in[6];
  const float* Wk    = (const float*)d_in[7];
  const float* Wv    = (const float*)d_in[8];
  const float* Wd1   = (const float*)d_in[9];
  const float* bnd1  = (const float*)d_in[10];
  const float* Wd2   = (const float*)d_in[11];
  const float* bnd2  = (const float*)d_in[12];
  const float* Wg1   = (const float*)d_in[13];
  const float* bng1  = (const float*)d_in[14];
  const float* Wg2   = (const float*)d_in[15];
  const float* bng2  = (const float*)d_in[16];
  float* out = (float*)d_out;

  float* ws   = (float*)d_ws;
  float* q_ws = ws;                           // B*N*DM each
  float* k_ws = q_ws + (size_t)NB*NN*DM;
  float* v_ws = k_ws + (size_t)NB*NN*DM;
  float* x_ws = v_ws + (size_t)NB*NN*DM;      // also res_ws after k_qkv
  float* sqn  = x_ws + (size_t)NB*NN*DM;
  int*   idx  = (int*)(sqn + (size_t)NB*NN);
  unsigned short* wfrag = (unsigned short*)(idx + (size_t)NB*NN*KK);
  // overlays (consumed before their hosts are written):
  unsigned short* cfrag = (unsigned short*)q_ws;   // knn candidate frags
  unsigned short* qfrag = (unsigned short*)k_ws;   // knn query frags
  float* fpm   = v_ws;                             // point-major f32 feats (B*N*64)
  int*   cand  = (int*)x_ws;                       // approx top-32 (B*N*32)

  k_sqnorm<<<(NB*NN)/256, 256, 0, stream>>>(feats, sqn);
  k_fprep <<<NB*(NN/64), 256, 0, stream>>>(feats, cfrag, qfrag, fpm);
  k_knn2  <<<NB*(NN/64), 256, 0, stream>>>(cfrag, qfrag, sqn, cand);
  k_refine<<<(NB*NN)/4, 256, 0, stream>>>(fpm, sqn, cand, idx);
  k_wprep <<<26, 256, 0, stream>>>(Wd1, bnd1, Wd2, bnd2, Wg1, bng1, Wg2, bng2, wfrag);
  k_x     <<<NB*(NN/64), 256, 0, stream>>>(feats, W1, bn1, x_ws);
  k_qkv   <<<NB*(NN/64), 256, 0, stream>>>(x_ws, Wq, Wk, Wv, q_ws, k_ws, v_ws);
  k_attn2 <<<(NB*NN)/(8*PPW), 512, 0, stream>>>(pos, q_ws, k_ws, v_ws, idx, wfrag,
                                                bnd1, bnd2, bng1, bng2, x_ws);
  k_out   <<<NB*(NN/128), 256, 0, stream>>>(x_ws, W2, bn2, feats, out);
}

// Round 5
// 1309.650 us; speedup vs baseline: 2.9395x; 1.0034x over previous
//
#include <hip/hip_runtime.h>
#include <cstdint>
#include <cstddef>

#define NB 4
#define NN 4096
#define KK 16
#define DP 64
#define DM 128
#define EPS 1e-5f

typedef __attribute__((ext_vector_type(8))) short bf16x8;
typedef __attribute__((ext_vector_type(4))) float f32x4;

__device__ __forceinline__ float lrelu(float x){ return x >= 0.f ? x : 0.2f*x; }

__device__ __forceinline__ unsigned short f2bf(float x){
  union { float f; uint32_t u; } a; a.f = x;
  return (unsigned short)((a.u + 0x7fffu + ((a.u >> 16) & 1u)) >> 16);
}
__device__ __forceinline__ float bf2f(unsigned short h){
  union { uint32_t u; float f; } a; a.u = ((uint32_t)h) << 16; return a.f;
}
__device__ __forceinline__ uint32_t pk2(float a, float b){
  return (uint32_t)f2bf(a) | ((uint32_t)f2bf(b) << 16);
}

__device__ __forceinline__ f32x4 mfma16(bf16x8 a, bf16x8 b, f32x4 c){
  return __builtin_amdgcn_mfma_f32_16x16x32_bf16(a, b, c, 0, 0, 0);
}
__device__ __forceinline__ float sx16(float v, int m){ return __shfl_xor(v, m, 16); }

// ---------------------------------------------------------------- sq norms
__global__ __launch_bounds__(256) void k_sqnorm(const float* __restrict__ feats,
                                                float* __restrict__ sqn){
  const int i = blockIdx.x*256 + threadIdx.x;
  const int b = i >> 12, n = i & (NN-1);
  const float* f = feats + (size_t)b*DP*NN + n;
  float s = 0.f;
  #pragma unroll
  for (int c=0;c<DP;c++){ const float v = f[(size_t)c*NN]; s += v*v; }
  sqn[i] = s;
}

// ---------------------------------------------------------------- feats -> bf16 hi/lo MFMA fragments + point-major f32 copy
__global__ __launch_bounds__(256) void k_fprep(const float* __restrict__ feats,
                                               unsigned short* __restrict__ cfrag,
                                               unsigned short* __restrict__ qfrag,
                                               float* __restrict__ fpm){
  __shared__ float ft[DP][65];
  const int t = threadIdx.x;
  const int b = blockIdx.x >> 6;
  const int n0 = (blockIdx.x & 63) * 64;
  for (int i=t; i<DP*64; i+=256){
    const int dim = i >> 6, pt = i & 63;
    ft[dim][pt] = feats[(size_t)b*DP*NN + (size_t)dim*NN + n0 + pt];
  }
  __syncthreads();
  // point-major f32 copy (coalesced refine reads)
  for (int i=t; i<64*DP; i+=256){
    const int pt = i >> 6, dim = i & 63;
    fpm[((size_t)(b*NN) + n0 + pt)*DP + dim] = ft[dim][pt];
  }
  #pragma unroll
  for (int v = t; v < 1024; v += 256){
    const int l = v & 63, hl = (v>>6)&1, ks = (v>>7)&1, ntl = v>>8;
    const int ptl = ntl*16 + (l&15);
    const int d0 = ks*32 + (l>>4)*8;
    unsigned short qo[8], co[8];
    #pragma unroll
    for (int j=0;j<8;j++){
      const float x = ft[d0+j][ptl];
      const unsigned short qh = f2bf(x);
      const float y = -2.f*x;
      const unsigned short ch = f2bf(y);
      qo[j] = hl ? f2bf(x - bf2f(qh)) : qh;
      co[j] = hl ? f2bf(y - bf2f(ch)) : ch;
    }
    const int nt = (n0 >> 4) + ntl;
    const size_t off = ((size_t)((b*256 + nt)*4 + ks*2 + hl))*512 + l*8;
    uint4 qv, cv;
    qv.x = (uint32_t)qo[0] | ((uint32_t)qo[1]<<16);
    qv.y = (uint32_t)qo[2] | ((uint32_t)qo[3]<<16);
    qv.z = (uint32_t)qo[4] | ((uint32_t)qo[5]<<16);
    qv.w = (uint32_t)qo[6] | ((uint32_t)qo[7]<<16);
    cv.x = (uint32_t)co[0] | ((uint32_t)co[1]<<16);
    cv.y = (uint32_t)co[2] | ((uint32_t)co[3]<<16);
    cv.z = (uint32_t)co[4] | ((uint32_t)co[5]<<16);
    cv.w = (uint32_t)co[6] | ((uint32_t)co[7]<<16);
    *reinterpret_cast<uint4*>(qfrag + off) = qv;
    *reinterpret_cast<uint4*>(cfrag + off) = cv;
  }
}

// ---------------------------------------------------------------- MFMA kNN: approx top-32 candidates per query
__global__ __launch_bounds__(256) void k_knn2(const unsigned short* __restrict__ cfrag,
                                              const unsigned short* __restrict__ qfrag,
                                              const float* __restrict__ sqn,
                                              int* __restrict__ cand){
  const int t = threadIdx.x, w = t >> 6, l = t & 63, g = l >> 4;
  const int b = blockIdx.x >> 6;
  const int qt = (blockIdx.x & 63)*4 + w;

  bf16x8 qf00, qf01, qf10, qf11;
  {
    const unsigned short* qb = qfrag + ((size_t)(b*256 + qt))*2048 + l*8;
    qf00 = *reinterpret_cast<const bf16x8*>(qb);
    qf01 = *reinterpret_cast<const bf16x8*>(qb + 512);
    qf10 = *reinterpret_cast<const bf16x8*>(qb + 1024);
    qf11 = *reinterpret_cast<const bf16x8*>(qb + 1536);
  }
  const unsigned short* cb = cfrag + ((size_t)(b*256))*2048 + l*8;

  float dd[16]; int ii[16];
  #pragma unroll
  for (int s=0;s<16;s++){ dd[s]=3.4e38f; ii[s]=0; }
  float dmax = 3.4e38f;

  bf16x8 c00 = *reinterpret_cast<const bf16x8*>(cb);
  bf16x8 c01 = *reinterpret_cast<const bf16x8*>(cb + 512);
  bf16x8 c10 = *reinterpret_cast<const bf16x8*>(cb + 1024);
  bf16x8 c11 = *reinterpret_cast<const bf16x8*>(cb + 1536);

  const float* sqb = sqn + b*NN + g*4;

  #pragma unroll 1
  for (int ct=0; ct<256; ++ct){
    bf16x8 n00, n01, n10, n11;
    if (ct < 255){
      const unsigned short* nb_ = cb + (size_t)(ct+1)*2048;
      n00 = *reinterpret_cast<const bf16x8*>(nb_);
      n01 = *reinterpret_cast<const bf16x8*>(nb_ + 512);
      n10 = *reinterpret_cast<const bf16x8*>(nb_ + 1024);
      n11 = *reinterpret_cast<const bf16x8*>(nb_ + 1536);
    }
    f32x4 acc = {0.f,0.f,0.f,0.f};
    acc = mfma16(c00, qf00, acc);
    acc = mfma16(c10, qf10, acc);
    acc = mfma16(c00, qf01, acc);
    acc = mfma16(c01, qf00, acc);
    acc = mfma16(c10, qf11, acc);
    acc = mfma16(c11, qf10, acc);
    const float4 sq4 = *reinterpret_cast<const float4*>(&sqb[ct*16]);
    const float d0 = acc[0] + sq4.x;
    const float d1 = acc[1] + sq4.y;
    const float d2 = acc[2] + sq4.z;
    const float d3 = acc[3] + sq4.w;
    const float mn = fminf(fminf(d0,d1), fminf(d2,d3));
    if (mn < dmax){
      const int cbase = ct*16 + g*4;
      float dv[4] = {d0,d1,d2,d3};
      #pragma unroll
      for (int u=0;u<4;u++){
        if (dv[u] < dmax){
          bool done=false;
          #pragma unroll
          for (int s=0;s<16;s++){
            if (!done && dd[s]==dmax){ dd[s]=dv[u]; ii[s]=cbase+u; done=true; }
          }
          dmax = dd[0];
          #pragma unroll
          for (int s=1;s<16;s++) dmax = fmaxf(dmax, dd[s]);
        }
      }
    }
    c00 = n00; c01 = n01; c10 = n10; c11 = n11;
  }

  // ---- merge across the 4 g-lanes per query: 32 extraction rounds
  const int q = qt*16 + (l & 15);
  int* op = cand + ((size_t)(b*NN) + q)*32;
  #pragma unroll 1
  for (int r=0; r<32; ++r){
    float bd = dd[0]; int bi = ii[0];
    #pragma unroll
    for (int s=1;s<16;s++){
      if (dd[s] < bd){ bd = dd[s]; bi = ii[s]; }
    }
    const int mi0 = bi;
    float od; int oi;
    od = __shfl_xor(bd, 16); oi = __shfl_xor(bi, 16);
    if (od < bd){ bd = od; bi = oi; }
    od = __shfl_xor(bd, 32); oi = __shfl_xor(bi, 32);
    if (od < bd){ bd = od; bi = oi; }
    const bool win = (bi == mi0);
    #pragma unroll
    for (int s=0;s<16;s++){
      if (win && ii[s]==bi) dd[s] = 3.4e38f;
    }
    if (g == 0) op[r] = bi;
  }
}

// ---------------------------------------------------------------- exact f32 refine: top-16 set from 32 candidates
__global__ __launch_bounds__(256) void k_refine(const float* __restrict__ fpm,
                                                const float* __restrict__ sqn,
                                                const int* __restrict__ cand,
                                                int* __restrict__ idx_ws){
  const int t = threadIdx.x, w = t >> 6, l = t & 63;
  const int q = blockIdx.x*4 + w;           // global point id b*NN+n
  const int b = q >> 12;
  const int c = l & 31, h = l >> 5;
  const int mi = cand[(size_t)q*32 + c];
  const float* qv = fpm + (size_t)q*DP + h*32;
  const float* cv = fpm + ((size_t)(b*NN) + mi)*DP + h*32;
  float dot = 0.f;
  #pragma unroll
  for (int d=0; d<32; d+=4){
    const float4 a = *reinterpret_cast<const float4*>(&qv[d]);
    const float4 x = *reinterpret_cast<const float4*>(&cv[d]);
    dot += a.x*x.x; dot += a.y*x.y; dot += a.z*x.z; dot += a.w*x.w;
  }
  dot += __shfl_xor(dot, 32);
  const float dist = sqn[q] + sqn[b*NN + mi] - 2.f*dot;
  int rank = 0;
  #pragma unroll
  for (int j=0; j<32; j++){
    const float dj = __shfl(dist, j);
    const int   ij = __shfl(mi,  j);
    rank += (dj < dist || (dj == dist && ij < mi)) ? 1 : 0;
  }
  if (h == 0 && rank < KK) idx_ws[(size_t)q*KK + rank] = mi;
}

// ---------------------------------------------------------------- x = lrelu(bn1(W1@feats)), point-major out
__global__ __launch_bounds__(256) void k_x(const float* __restrict__ feats,
                                           const float* __restrict__ W1,
                                           const float* __restrict__ bn1,
                                           float* __restrict__ x_ws){
  __shared__ float W1s[DM][DP+1];
  __shared__ float ft[DP][64];
  __shared__ float bS[DM], bT[DM];
  const int t = threadIdx.x;
  const int b = blockIdx.x >> 6;
  const int n0 = (blockIdx.x & 63) * 64;
  for (int i=t; i<DM*DP; i+=256){ W1s[i>>6][i&63] = W1[i]; }
  if (t < DM){
    float g = bn1[t], be = bn1[DM+t], mn = bn1[2*DM+t], vr = bn1[3*DM+t];
    float s = g*rsqrtf(vr+EPS); bS[t]=s; bT[t]=be-mn*s;
  }
  for (int i=t; i<DP*64; i+=256){
    const int c = i>>6, j = i&63;
    ft[c][j] = feats[(size_t)b*DP*NN + (size_t)c*NN + n0 + j];
  }
  __syncthreads();
  const int j = t >> 2, cq = t & 3;
  float acc[32];
  #pragma unroll
  for (int i=0;i<32;i++) acc[i]=0.f;
  for (int c=0;c<DP;c++){
    const float fv = ft[c][j];
    #pragma unroll
    for (int i=0;i<32;i++) acc[i] += W1s[cq+4*i][c]*fv;
  }
  float* xo = x_ws + ((size_t)(b*NN) + n0 + j)*DM;
  #pragma unroll
  for (int i=0;i<32;i++){
    const int ch = cq + 4*i;
    xo[ch] = lrelu(acc[i]*bS[ch] + bT[ch]);
  }
}

// ---------------------------------------------------------------- q/k/v = W{q,k,v} @ x, point-major out
__global__ __launch_bounds__(256) void k_qkv(const float* __restrict__ x_ws,
                                             const float* __restrict__ Wq,
                                             const float* __restrict__ Wk,
                                             const float* __restrict__ Wv,
                                             float* __restrict__ q_ws,
                                             float* __restrict__ k_ws,
                                             float* __restrict__ v_ws){
  __shared__ float Ws[DM][DM+4];
  __shared__ float xt[64][DM+4];
  const int t = threadIdx.x;
  const int b = blockIdx.x >> 6;
  const int n0 = (blockIdx.x & 63) * 64;
  for (int i=t; i<64*DM; i+=256){
    const int j = i>>7, c = i&127;
    xt[j][c] = x_ws[((size_t)(b*NN) + n0 + j)*DM + c];
  }
  const float* Wp[3] = {Wq, Wk, Wv};
  float* Op[3] = {q_ws, k_ws, v_ws};
  for (int wi=0; wi<3; wi++){
    __syncthreads();
    for (int i=t; i<DM*DM; i+=256){ Ws[i>>7][i&127] = Wp[wi][i]; }
    __syncthreads();
    const int j = t>>2, cq = t&3;
    float acc[32];
    #pragma unroll
    for (int i=0;i<32;i++) acc[i]=0.f;
    for (int c=0;c<DM;c+=4){
      const float4 xv = *reinterpret_cast<const float4*>(&xt[j][c]);
      #pragma unroll
      for (int i=0;i<32;i++){
        const float4 wv = *reinterpret_cast<const float4*>(&Ws[cq+4*i][c]);
        acc[i] += wv.x*xv.x + wv.y*xv.y + wv.z*xv.z + wv.w*xv.w;
      }
    }
    float* op = Op[wi] + ((size_t)(b*NN) + n0 + j)*DM;
    #pragma unroll
    for (int i=0;i<32;i++) op[cq+4*i] = acc[i];
  }
}

// ---------------------------------------------------------------- weight prep: bf16 MFMA fragments, bn-scale folded
__global__ __launch_bounds__(256) void k_wprep(
    const float* __restrict__ Wd1, const float* __restrict__ bnd1,
    const float* __restrict__ Wd2, const float* __restrict__ bnd2,
    const float* __restrict__ Wg1, const float* __restrict__ bng1,
    const float* __restrict__ Wg2, const float* __restrict__ bng2,
    unsigned short* __restrict__ wfrag){
  const int i = blockIdx.x*256 + threadIdx.x;
  if (i >= 104*64) return;
  const int f = i >> 6, l = i & 63;
  const int r16 = l & 15, kg = (l >> 4) * 8;
  unsigned short o8[8];
  if (f < 96){
    const int mat = f >> 5, tt = (f >> 2) & 7, ks = f & 3;
    const float* W; const float* bn;
    if (mat == 0){ W = Wd2; bn = bnd2; }
    else if (mat == 1){ W = Wg1; bn = bng1; }
    else { W = Wg2; bn = bng2; }
    const int row = tt*16 + r16;
    const float s = bn[row] * rsqrtf(bn[3*DM+row] + EPS);
    const float* src = W + (size_t)row*DM + ks*32 + kg;
    #pragma unroll
    for (int j=0;j<8;j++) o8[j] = f2bf(s * src[j]);
  } else {
    const int tt = f - 96;
    const int row = tt*16 + r16;
    const float s = bnd1[row] * rsqrtf(bnd1[3*DM+row] + EPS);
    #pragma unroll
    for (int j=0;j<8;j++){
      const int k = kg + j;
      o8[j] = (k < 3) ? f2bf(s * Wd1[row*3 + k]) : (unsigned short)0;
    }
  }
  uint4 v;
  v.x = (uint32_t)o8[0] | ((uint32_t)o8[1]<<16);
  v.y = (uint32_t)o8[2] | ((uint32_t)o8[3]<<16);
  v.z = (uint32_t)o8[4] | ((uint32_t)o8[5]<<16);
  v.w = (uint32_t)o8[6] | ((uint32_t)o8[7]<<16);
  *reinterpret_cast<uint4*>(wfrag + (size_t)i*8) = v;
}

// ---------------------------------------------------------------- fused MFMA attention
// __launch_bounds__(512, 2): LDS (141 KB) already caps at 1 block/CU = 2 waves/SIMD,
// so allow the full 256-VGPR budget -> no scratch spills (R4: WRITE_SIZE 467 MB of spill traffic).
#define PPW 4
__global__ __launch_bounds__(512, 2) void k_attn2(
    const float* __restrict__ pos, const float* __restrict__ q_ws,
    const float* __restrict__ k_ws, const float* __restrict__ v_ws,
    const int* __restrict__ idx_ws, const unsigned short* __restrict__ wfrag,
    const float* __restrict__ bnd1, const float* __restrict__ bnd2,
    const float* __restrict__ bng1, const float* __restrict__ bng2,
    float* __restrict__ res_ws){
  __shared__ __align__(16) unsigned short Wf[104*512];
  __shared__ __align__(16) unsigned short Hb[8][2048];
  __shared__ float bnT[4][DM];

  const int t = threadIdx.x;
  for (int i = t; i < (104*512)/8; i += 512)
    reinterpret_cast<uint4*>(Wf)[i] = reinterpret_cast<const uint4*>(wfrag)[i];
  if (t < DM){
    const float* bp[4] = {bnd1, bnd2, bng1, bng2};
    #pragma unroll
    for (int s4=0;s4<4;s4++){
      const float g = bp[s4][t], be = bp[s4][DM+t], mn = bp[s4][2*DM+t], vr = bp[s4][3*DM+t];
      const float sc = g * rsqrtf(vr + EPS);
      bnT[s4][t] = be - mn*sc;
    }
  }
  __syncthreads();

  const int w = t >> 6, l = t & 63;
  const int p = l & 15, g = l >> 4;
  unsigned short* hb = Hb[w];
  const int hwb = p*128 + ((g & 1) * 4);

  #pragma unroll 1
  for (int pp = 0; pp < PPW; ++pp){
    const int gp = blockIdx.x*(8*PPW) + w*PPW + pp;
    const int b = gp >> 12, n = gp & (NN-1);
    const int mi = idx_ws[gp*KK + p];
    union { bf16x8 v; uint32_t u[4]; } bu;
    bu.u[0] = 0; bu.u[1] = 0; bu.u[2] = 0; bu.u[3] = 0;
    if (g == 0){
      const float* posb = pos + (size_t)b*3*NN;
      const float rx = posb[n]      - posb[mi];
      const float ry = posb[NN+n]   - posb[NN+mi];
      const float rz = posb[2*NN+n] - posb[2*NN+mi];
      bu.u[0] = pk2(rx, ry);
      bu.u[1] = pk2(rz, 0.f);
    }
    #pragma unroll
    for (int tt=0; tt<8; ++tt){
      f32x4 acc = {0.f,0.f,0.f,0.f};
      const bf16x8 a = *reinterpret_cast<const bf16x8*>(&Wf[(96+tt)*512 + l*8]);
      acc = mfma16(a, bu.v, acc);
      const f32x4 sh = *reinterpret_cast<const f32x4*>(&bnT[0][tt*16 + g*4]);
      const int gw = tt*2 + (g>>1);
      uint2 hp;
      hp.x = pk2(lrelu(acc[0]+sh[0]), lrelu(acc[1]+sh[1]));
      hp.y = pk2(lrelu(acc[2]+sh[2]), lrelu(acc[3]+sh[3]));
      *reinterpret_cast<uint2*>(&hb[hwb + (gw^p)*8]) = hp;
    }
    float pe[32];
    {
      const bf16x8 b0 = *reinterpret_cast<const bf16x8*>(&hb[p*128 + ((0*4+g)^p)*8]);
      const bf16x8 b1 = *reinterpret_cast<const bf16x8*>(&hb[p*128 + ((1*4+g)^p)*8]);
      const bf16x8 b2 = *reinterpret_cast<const bf16x8*>(&hb[p*128 + ((2*4+g)^p)*8]);
      const bf16x8 b3 = *reinterpret_cast<const bf16x8*>(&hb[p*128 + ((3*4+g)^p)*8]);
      #pragma unroll
      for (int tt=0; tt<8; ++tt){
        f32x4 acc = {0.f,0.f,0.f,0.f};
        acc = mfma16(*reinterpret_cast<const bf16x8*>(&Wf[(0*32+tt*4+0)*512 + l*8]), b0, acc);
        acc = mfma16(*reinterpret_cast<const bf16x8*>(&Wf[(0*32+tt*4+1)*512 + l*8]), b1, acc);
        acc = mfma16(*reinterpret_cast<const bf16x8*>(&Wf[(0*32+tt*4+2)*512 + l*8]), b2, acc);
        acc = mfma16(*reinterpret_cast<const bf16x8*>(&Wf[(0*32+tt*4+3)*512 + l*8]), b3, acc);
        const f32x4 sh = *reinterpret_cast<const f32x4*>(&bnT[1][tt*16 + g*4]);
        pe[tt*4+0] = lrelu(acc[0]+sh[0]);
        pe[tt*4+1] = lrelu(acc[1]+sh[1]);
        pe[tt*4+2] = lrelu(acc[2]+sh[2]);
        pe[tt*4+3] = lrelu(acc[3]+sh[3]);
      }
    }
    const float* qrow = q_ws + (size_t)gp*DM;
    const float* krow = k_ws + ((size_t)(b*NN) + mi)*DM;
    #pragma unroll
    for (int tt=0; tt<8; ++tt){
      const float4 qv = *reinterpret_cast<const float4*>(&qrow[tt*16 + g*4]);
      const float4 kv = *reinterpret_cast<const float4*>(&krow[tt*16 + g*4]);
      const int gw = tt*2 + (g>>1);
      uint2 hp;
      hp.x = pk2(qv.x - kv.x + pe[tt*4+0], qv.y - kv.y + pe[tt*4+1]);
      hp.y = pk2(qv.z - kv.z + pe[tt*4+2], qv.w - kv.w + pe[tt*4+3]);
      *reinterpret_cast<uint2*>(&hb[hwb + (gw^p)*8]) = hp;
    }
    {
      const bf16x8 b0 = *reinterpret_cast<const bf16x8*>(&hb[p*128 + ((0*4+g)^p)*8]);
      const bf16x8 b1 = *reinterpret_cast<const bf16x8*>(&hb[p*128 + ((1*4+g)^p)*8]);
      const bf16x8 b2 = *reinterpret_cast<const bf16x8*>(&hb[p*128 + ((2*4+g)^p)*8]);
      const bf16x8 b3 = *reinterpret_cast<const bf16x8*>(&hb[p*128 + ((3*4+g)^p)*8]);
      #pragma unroll
      for (int tt=0; tt<8; ++tt){
        f32x4 acc = {0.f,0.f,0.f,0.f};
        acc = mfma16(*reinterpret_cast<const bf16x8*>(&Wf[(1*32+tt*4+0)*512 + l*8]), b0, acc);
        acc = mfma16(*reinterpret_cast<const bf16x8*>(&Wf[(1*32+tt*4+1)*512 + l*8]), b1, acc);
        acc = mfma16(*reinterpret_cast<const bf16x8*>(&Wf[(1*32+tt*4+2)*512 + l*8]), b2, acc);
        acc = mfma16(*reinterpret_cast<const bf16x8*>(&Wf[(1*32+tt*4+3)*512 + l*8]), b3, acc);
        const f32x4 sh = *reinterpret_cast<const f32x4*>(&bnT[2][tt*16 + g*4]);
        const int gw = tt*2 + (g>>1);
        uint2 hp;
        hp.x = pk2(lrelu(acc[0]+sh[0]), lrelu(acc[1]+sh[1]));
        hp.y = pk2(lrelu(acc[2]+sh[2]), lrelu(acc[3]+sh[3]));
        *reinterpret_cast<uint2*>(&hb[hwb + (gw^p)*8]) = hp;
      }
    }
    float e[32];
    {
      const bf16x8 b0 = *reinterpret_cast<const bf16x8*>(&hb[p*128 + ((0*4+g)^p)*8]);
      const bf16x8 b1 = *reinterpret_cast<const bf16x8*>(&hb[p*128 + ((1*4+g)^p)*8]);
      const bf16x8 b2 = *reinterpret_cast<const bf16x8*>(&hb[p*128 + ((2*4+g)^p)*8]);
      const bf16x8 b3 = *reinterpret_cast<const bf16x8*>(&hb[p*128 + ((3*4+g)^p)*8]);
      #pragma unroll
      for (int tt=0; tt<8; ++tt){
        f32x4 acc = {0.f,0.f,0.f,0.f};
        acc = mfma16(*reinterpret_cast<const bf16x8*>(&Wf[(2*32+tt*4+0)*512 + l*8]), b0, acc);
        acc = mfma16(*reinterpret_cast<const bf16x8*>(&Wf[(2*32+tt*4+1)*512 + l*8]), b1, acc);
        acc = mfma16(*reinterpret_cast<const bf16x8*>(&Wf[(2*32+tt*4+2)*512 + l*8]), b2, acc);
        acc = mfma16(*reinterpret_cast<const bf16x8*>(&Wf[(2*32+tt*4+3)*512 + l*8]), b3, acc);
        const f32x4 sh = *reinterpret_cast<const f32x4*>(&bnT[3][tt*16 + g*4]);
        e[tt*4+0] = lrelu(acc[0]+sh[0]) * 0.015625f;
        e[tt*4+1] = lrelu(acc[1]+sh[1]) * 0.015625f;
        e[tt*4+2] = lrelu(acc[2]+sh[2]) * 0.015625f;
        e[tt*4+3] = lrelu(acc[3]+sh[3]) * 0.015625f;
      }
    }
    float m = e[0];
    #pragma unroll
    for (int i=1;i<32;i++) m = fmaxf(m, e[i]);
    #pragma unroll
    for (int mk=1; mk<16; mk<<=1) m = fmaxf(m, sx16(m, mk));
    #pragma unroll
    for (int i=0;i<32;i++) e[i] = __expf(e[i] - m);
    const float* vrow = v_ws + ((size_t)(b*NN) + mi)*DM;
    #pragma unroll
    for (int tt=0; tt<8; ++tt){
      const float4 vv = *reinterpret_cast<const float4*>(&vrow[tt*16 + g*4]);
      #pragma unroll
      for (int r=0;r<4;r++){
        const int i = tt*4 + r;
        const float vr4 = (r==0?vv.x : r==1?vv.y : r==2?vv.z : vv.w);
        float num = e[i] * (vr4 + pe[i]);
        float den = e[i];
        #pragma unroll
        for (int mk=1; mk<16; mk<<=1){ num += sx16(num, mk); den += sx16(den, mk); }
        pe[i] = num * __builtin_amdgcn_rcpf(den);
      }
    }
    if (p == 0){
      #pragma unroll
      for (int tt=0; tt<8; ++tt){
        float4 o;
        o.x = pe[tt*4+0]; o.y = pe[tt*4+1]; o.z = pe[tt*4+2]; o.w = pe[tt*4+3];
        *reinterpret_cast<float4*>(&res_ws[(size_t)gp*DM + tt*16 + g*4]) = o;
      }
    }
  }
}

// ---------------------------------------------------------------- out = lrelu(bn2(W2@res)) + feats
__global__ __launch_bounds__(256) void k_out(const float* __restrict__ res_ws,
                                             const float* __restrict__ W2,
                                             const float* __restrict__ bn2,
                                             const float* __restrict__ feats,
                                             float* __restrict__ out){
  __shared__ float W2s[DP][DM+4];
  __shared__ float rt[128][DM+4];
  __shared__ float ob[DP][132];
  __shared__ float bS[DP], bT[DP];
  const int t = threadIdx.x;
  const int b = blockIdx.x >> 5;
  const int n0 = (blockIdx.x & 31) * 128;
  for (int i=t; i<DP*DM; i+=256){ W2s[i>>7][i&127] = W2[i]; }
  if (t < DP){
    float g=bn2[t], be=bn2[DP+t], mn=bn2[2*DP+t], vr=bn2[3*DP+t];
    float s = g*rsqrtf(vr+EPS); bS[t]=s; bT[t]=be-mn*s;
  }
  for (int i=t; i<128*DM; i+=256){
    const int j=i>>7, c=i&127;
    rt[j][c] = res_ws[((size_t)(b*NN)+n0+j)*DM + c];
  }
  __syncthreads();
  const int j = t>>1, cq = t&1;
  float acc[32];
  #pragma unroll
  for (int i=0;i<32;i++) acc[i]=0.f;
  for (int c=0;c<DM;c+=4){
    const float4 rv = *reinterpret_cast<const float4*>(&rt[j][c]);
    #pragma unroll
    for (int i=0;i<32;i++){
      const float4 wv = *reinterpret_cast<const float4*>(&W2s[cq+2*i][c]);
      acc[i] += wv.x*rv.x + wv.y*rv.y + wv.z*rv.z + wv.w*rv.w;
    }
  }
  #pragma unroll
  for (int i=0;i<32;i++) ob[cq+2*i][j] = acc[i];
  __syncthreads();
  for (int i=t; i<DP*128; i+=256){
    const int ch=i>>7, jj=i&127;
    const size_t o = (size_t)b*DP*NN + (size_t)ch*NN + n0 + jj;
    out[o] = lrelu(ob[ch][jj]*bS[ch] + bT[ch]) + feats[o];
  }
}

// ----------------------------------------------------------------
extern "C" void kernel_launch(void* const* d_in, const int* in_sizes, int n_in,
                              void* d_out, int out_size, void* d_ws, size_t ws_size,
                              hipStream_t stream) {
  const float* feats = (const float*)d_in[0];
  const float* pos   = (const float*)d_in[1];
  const float* W1    = (const float*)d_in[2];
  const float* bn1   = (const float*)d_in[3];
  const float* W2    = (const float*)d_in[4];
  const float* bn2   = (const float*)d_in[5];
  const float* Wq    = (const float*)d_in[6];
  const float* Wk    = (const float*)d_in[7];
  const float* Wv    = (const float*)d_in[8];
  const float* Wd1   = (const float*)d_in[9];
  const float* bnd1  = (const float*)d_in[10];
  const float* Wd2   = (const float*)d_in[11];
  const float* bnd2  = (const float*)d_in[12];
  const float* Wg1   = (const float*)d_in[13];
  const float* bng1  = (const float*)d_in[14];
  const float* Wg2   = (const float*)d_in[15];
  const float* bng2  = (const float*)d_in[16];
  float* out = (float*)d_out;

  float* ws   = (float*)d_ws;
  float* q_ws = ws;                           // B*N*DM each
  float* k_ws = q_ws + (size_t)NB*NN*DM;
  float* v_ws = k_ws + (size_t)NB*NN*DM;
  float* x_ws = v_ws + (size_t)NB*NN*DM;      // also res_ws after k_qkv
  float* sqn  = x_ws + (size_t)NB*NN*DM;
  int*   idx  = (int*)(sqn + (size_t)NB*NN);
  unsigned short* wfrag = (unsigned short*)(idx + (size_t)NB*NN*KK);
  // overlays (consumed before their hosts are written):
  unsigned short* cfrag = (unsigned short*)q_ws;   // knn candidate frags
  unsigned short* qfrag = (unsigned short*)k_ws;   // knn query frags
  float* fpm   = v_ws;                             // point-major f32 feats (B*N*64)
  int*   cand  = (int*)x_ws;                       // approx top-32 (B*N*32)

  k_sqnorm<<<(NB*NN)/256, 256, 0, stream>>>(feats, sqn);
  k_fprep <<<NB*(NN/64), 256, 0, stream>>>(feats, cfrag, qfrag, fpm);
  k_knn2  <<<NB*(NN/64), 256, 0, stream>>>(cfrag, qfrag, sqn, cand);
  k_refine<<<(NB*NN)/4, 256, 0, stream>>>(fpm, sqn, cand, idx);
  k_wprep <<<26, 256, 0, stream>>>(Wd1, bnd1, Wd2, bnd2, Wg1, bng1, Wg2, bng2, wfrag);
  k_x     <<<NB*(NN/64), 256, 0, stream>>>(feats, W1, bn1, x_ws);
  k_qkv   <<<NB*(NN/64), 256, 0, stream>>>(x_ws, Wq, Wk, Wv, q_ws, k_ws, v_ws);
  k_attn2 <<<(NB*NN)/(8*PPW), 512, 0, stream>>>(pos, q_ws, k_ws, v_ws, idx, wfrag,
                                                bnd1, bnd2, bng1, bng2, x_ws);
  k_out   <<<NB*(NN/128), 256, 0, stream>>>(x_ws, W2, bn2, feats, out);
}